// Round 17
// baseline (824.457 us; speedup 1.0000x reference)
//
#include <hip/hip_runtime.h>
#include <hip/hip_fp16.h>
#include <math.h>
#include <stdio.h>
#include <stdint.h>

#define N_SRC 200000
#define N_DST 100000
#define NE    400000
// IN=128, H=8, D=32, H*D=256

#define SCAN_CHUNK 1024
#define NSCAN ((N_DST + SCAN_CHUNK - 1) / SCAN_CHUNK)   // 98

typedef short bf16x8 __attribute__((ext_vector_type(8)));
typedef float f32x4 __attribute__((ext_vector_type(4)));

__device__ __forceinline__ float bflo(unsigned int u) { return __uint_as_float(u << 16); }
__device__ __forceinline__ float bfhi(unsigned int u) { return __uint_as_float(u & 0xFFFF0000u); }
__device__ __forceinline__ unsigned short f2bf(float f) {
    unsigned int u = __float_as_uint(f);
    u += 0x7FFFu + ((u >> 16) & 1u);       // round-to-nearest-even
    return (unsigned short)(u >> 16);
}
__device__ __forceinline__ unsigned int packbf(float f0, float f1) {
    return __builtin_amdgcn_perm(__float_as_uint(f1), __float_as_uint(f0), 0x07060302u);
}
// f32 -> fp8 e5m2 (via f16 RNE, then RNE to top 8 bits)
__device__ __forceinline__ unsigned char f2e5(float f) {
    __half h = __float2half(f);
    unsigned short b = *reinterpret_cast<unsigned short*>(&h);
    b = (unsigned short)(b + 0x7Fu + ((b >> 8) & 1u));
    return (unsigned char)(b >> 8);
}
// fp8 e5m2 -> f32
__device__ __forceinline__ float e52f(unsigned int b8) {
    unsigned short h = (unsigned short)(b8 << 8);
    __half hh = *reinterpret_cast<__half*>(&h);
    return __half2float(hh);
}
// async global->LDS DMA, 16 bytes per lane
__device__ __forceinline__ void gl2lds(const void* g, void* l) {
    __builtin_amdgcn_global_load_lds(
        (const __attribute__((address_space(1))) unsigned int*)g,
        (__attribute__((address_space(3))) unsigned int*)l, 16, 0, 0);
}

// ---------------------------------------------------------------------------
// Generic fused GEMM body (device function, one tile of 128 rows x 128 cols).
// A via gl_lds double-buffer (source-swizzled chunks); B-fragments loaded to
// REGISTERS per step from L2 (issued BEFORE the A-stage so compiler pb-waits
// leave the prefetched A in flight: entry 4 oldA -> +8 B -> +4 newA;
// vmcnt(12) drains exactly oldA; pb uses drain to vmcnt(4)).
// Epilogue writes bf16 (out_lin) / fp8-e5m2 exp (out_exp); optional T-tile in
// LDS feeding FUSEV (v = sf@Wv^T + b_v) and DOT (8-head row dots).
// ---------------------------------------------------------------------------
template<int K, int KP, int NT, bool FUSEV, bool DOT>
__device__ __forceinline__ void gemm_body(
    int tileY, char* LDSB,
    const float* __restrict__ Ap, const unsigned short* __restrict__ Wf,
    const float* __restrict__ bias, const float* __restrict__ add_n,
    const float* __restrict__ add_c,
    unsigned short* __restrict__ out_lin, unsigned char* __restrict__ out_exp,
    const unsigned short* __restrict__ wvfrag, const float* __restrict__ bv,
    unsigned short* __restrict__ vout,
    const unsigned short* __restrict__ dotfrag, float* __restrict__ dotout,
    int N, int C)
{
    constexpr int KST = KP / 32;
    char* As = LDSB;            // 2 x 16384 (f32 A step)
    char* T  = LDSB;            // 128 x 256B bf16 sf tile (reused after main)

    const int tid  = threadIdx.x;
    const int lane = tid & 63;
    const int wv   = tid >> 6;
    const int fr   = lane & 15;
    const int fq   = lane >> 4;
    const int row0 = tileY * 128;
    const int NTC  = C / 16;

    f32x4 acc[2][NT];
#pragma unroll
    for (int m = 0; m < 2; ++m)
#pragma unroll
        for (int n = 0; n < NT; ++n) acc[m][n] = (f32x4){0.f, 0.f, 0.f, 0.f};

    const int csw = (lane & 7) ^ (lane >> 3);   // source-swizzled chunk (A stage)

    auto stageA = [&](int buf, int ks) {
        char* ab = As + buf * 16384;
        const char* Af = (const char*)Ap;
#pragma unroll
        for (int q = 0; q < 4; ++q) {
            int i   = wv * 4 + q;
            int row = i * 8 + (lane >> 3);
            int rr  = row0 + row; if (rr >= N) rr = N - 1;
            int kk  = ks * 32 + csw * 4;
            long off = (long)rr * K + ((kk + 4 <= K) ? kk : 0);
            gl2lds(Af + off * 4, ab + i * 1024 + lane * 16);
        }
    };

    stageA(0, 0);
    for (int ks = 0; ks < KST; ++ks) {
        const int cur = ks & 1;
        // B fragments -> registers (issued FIRST so pb-waits don't drain newA)
        uint4 pb[NT];
#pragma unroll
        for (int n = 0; n < NT; ++n)
            pb[n] = *(const uint4*)&Wf[(((size_t)ks * NTC + n) * 64 + lane) * 8];
        if (ks + 1 < KST) {
            stageA(cur ^ 1, ks + 1);
            asm volatile("s_waitcnt vmcnt(12)" ::: "memory");
        } else {
            asm volatile("s_waitcnt vmcnt(8)" ::: "memory");
        }
        __builtin_amdgcn_s_barrier();

        const char* ab = As + cur * 16384;
        const int rA = fr & 7;
        float4 f0 = *(const float4*)(ab + (wv * 32 +      fr) * 128 + ((2 * fq)     ^ rA) * 16);
        float4 f1 = *(const float4*)(ab + (wv * 32 +      fr) * 128 + ((2 * fq + 1) ^ rA) * 16);
        float4 f2 = *(const float4*)(ab + (wv * 32 + 16 + fr) * 128 + ((2 * fq)     ^ rA) * 16);
        float4 f3 = *(const float4*)(ab + (wv * 32 + 16 + fr) * 128 + ((2 * fq + 1) ^ rA) * 16);
        uint4 u0, u1;
        u0.x = packbf(f0.x, f0.y); u0.y = packbf(f0.z, f0.w);
        u0.z = packbf(f1.x, f1.y); u0.w = packbf(f1.z, f1.w);
        u1.x = packbf(f2.x, f2.y); u1.y = packbf(f2.z, f2.w);
        u1.z = packbf(f3.x, f3.y); u1.w = packbf(f3.z, f3.w);
        bf16x8 a0 = *(bf16x8*)&u0;
        bf16x8 a1 = *(bf16x8*)&u1;
#pragma unroll
        for (int n = 0; n < NT; ++n) {
            acc[0][n] = __builtin_amdgcn_mfma_f32_16x16x32_bf16(a0, *(bf16x8*)&pb[n], acc[0][n], 0, 0, 0);
            acc[1][n] = __builtin_amdgcn_mfma_f32_16x16x32_bf16(a1, *(bf16x8*)&pb[n], acc[1][n], 0, 0, 0);
        }
        asm volatile("s_waitcnt lgkmcnt(0)" ::: "memory");
        __builtin_amdgcn_s_barrier();
    }

    // ---- main epilogue: D col = lane&15, row = (lane>>4)*4 + reg (m89/m91) ----
    float bc[NT];
#pragma unroll
    for (int n = 0; n < NT; ++n) {
        int col = n * 16 + fr;
        float b = 0.f;
        if (bias)  b += bias[col];
        if (add_c) b += add_c[col];
        bc[n] = b;
    }
#pragma unroll
    for (int m = 0; m < 2; ++m) {
#pragma unroll
        for (int j = 0; j < 4; ++j) {
            int rl  = wv * 32 + m * 16 + fq * 4 + j;   // local row
            int row = row0 + rl;
            bool rok = (row < N);
#pragma unroll
            for (int n = 0; n < NT; ++n) {
                int col = n * 16 + fr;
                float v = acc[m][n][j] + bc[n];
                if (add_n && rok) v += add_n[(long)row * C + col];
                unsigned short bf = f2bf(v);
                if (FUSEV || DOT) {
                    int c = col >> 3;
                    *(unsigned short*)(T + rl * 256 + ((c ^ (rl & 7)) * 16) + (col & 7) * 2) = bf;
                }
                if (rok) {
                    long o = (long)row * C + col;
                    if (out_lin) out_lin[o] = bf;
                    if (out_exp) out_exp[o] = f2e5(expf(v));
                }
            }
        }
    }

    if (FUSEV || DOT) {
        __syncthreads();    // T fully written
        auto tfrag = [&](int r, int c) -> bf16x8 {
            return *(const bf16x8*)(T + r * 256 + ((c ^ (r & 7)) * 16));
        };
        if (DOT) {
            f32x4 da[2];
            da[0] = (f32x4){0.f, 0.f, 0.f, 0.f};
            da[1] = (f32x4){0.f, 0.f, 0.f, 0.f};
#pragma unroll
            for (int ks = 0; ks < 4; ++ks) {
                bf16x8 bf = *(const bf16x8*)&dotfrag[((size_t)ks * 64 + lane) * 8];
                bf16x8 t0 = tfrag(wv * 32 +      fr, ks * 4 + fq);
                bf16x8 t1 = tfrag(wv * 32 + 16 + fr, ks * 4 + fq);
                da[0] = __builtin_amdgcn_mfma_f32_16x16x32_bf16(t0, bf, da[0], 0, 0, 0);
                da[1] = __builtin_amdgcn_mfma_f32_16x16x32_bf16(t1, bf, da[1], 0, 0, 0);
            }
#pragma unroll
            for (int m = 0; m < 2; ++m)
#pragma unroll
                for (int j = 0; j < 4; ++j) {
                    int row = row0 + wv * 32 + m * 16 + fq * 4 + j;
                    if (fr < 8 && row < N) dotout[(long)row * 8 + fr] = da[m][j];
                }
        }
        if (FUSEV) {
#pragma unroll
            for (int half = 0; half < 2; ++half) {
                f32x4 va[2][8];
#pragma unroll
                for (int m = 0; m < 2; ++m)
#pragma unroll
                    for (int n = 0; n < 8; ++n) va[m][n] = (f32x4){0.f, 0.f, 0.f, 0.f};
#pragma unroll
                for (int ks = 0; ks < 4; ++ks) {
                    bf16x8 t0 = tfrag(wv * 32 +      fr, ks * 4 + fq);
                    bf16x8 t1 = tfrag(wv * 32 + 16 + fr, ks * 4 + fq);
                    uint4 vb4[8];
#pragma unroll
                    for (int n = 0; n < 8; ++n)
                        vb4[n] = *(const uint4*)&wvfrag[(((size_t)ks * 16 + half * 8 + n) * 64 + lane) * 8];
#pragma unroll
                    for (int n = 0; n < 8; ++n) {
                        va[0][n] = __builtin_amdgcn_mfma_f32_16x16x32_bf16(t0, *(bf16x8*)&vb4[n], va[0][n], 0, 0, 0);
                        va[1][n] = __builtin_amdgcn_mfma_f32_16x16x32_bf16(t1, *(bf16x8*)&vb4[n], va[1][n], 0, 0, 0);
                    }
                }
#pragma unroll
                for (int m = 0; m < 2; ++m)
#pragma unroll
                    for (int j = 0; j < 4; ++j) {
                        int row = row0 + wv * 32 + m * 16 + fq * 4 + j;
                        if (row >= N) continue;
#pragma unroll
                        for (int n = 0; n < 8; ++n) {
                            int col = half * 128 + n * 16 + fr;
                            vout[(long)row * 256 + col] = f2bf(va[m][n][j] + bv[col]);
                        }
                    }
            }
        }
    }
}

// ---------------------------------------------------------------------------
// Merged triple-GEMM dispatch — BYTE-IDENTICAL to round 13 (7 buckets, no
// hist inside; hist stays a separate kernel so gemm_body codegen and the
// counted-vmcnt invariant are untouched).
// ---------------------------------------------------------------------------
__global__ __launch_bounds__(256) void gemm_all(
    const float* __restrict__ x_user, const unsigned short* __restrict__ wub,
    const float* __restrict__ b_nf_user, const float* __restrict__ node_emb_user,
    const float* __restrict__ edge_emb,
    unsigned char* __restrict__ esf8,
    const unsigned short* __restrict__ wvb, const float* __restrict__ bv,
    unsigned short* __restrict__ v_b,
    const unsigned short* __restrict__ wkf, float* __restrict__ ak,
    const float* __restrict__ x_item, const unsigned short* __restrict__ wib,
    const float* __restrict__ b_nf_item,
    const unsigned short* __restrict__ wqf, float* __restrict__ aq,
    const float* __restrict__ edge_feats, const unsigned short* __restrict__ web,
    const float* __restrict__ b_ef, unsigned char* __restrict__ P8)
{
    __shared__ __align__(16) char LDSB[32768];
    int gid = blockIdx.x;
    int b = gid / 7;
    int r = gid - b * 7;
    if (r < 2) {
        int t = b * 2 + r;
        if (t < 1563)
            gemm_body<300, 320, 8, true, true>(t, LDSB,
                x_user, wub, b_nf_user, node_emb_user, edge_emb,
                nullptr, esf8, wvb, bv, v_b, wkf, ak, N_SRC, 128);
    } else if (r == 2) {
        gemm_body<200, 224, 8, false, true>(b, LDSB,
            x_item, wib, b_nf_item, nullptr, edge_emb,
            nullptr, nullptr, nullptr, nullptr, nullptr, wqf, aq, N_DST, 128);
    } else {
        int t = b * 4 + (r - 3);
        if (t < 3125)
            gemm_body<64, 64, 8, false, false>(t, LDSB,
                edge_feats, web, b_ef, nullptr, nullptr,
                nullptr, P8, nullptr, nullptr, nullptr, nullptr, nullptr, NE, 128);
    }
}

// ---------------------------------------------------------------------------
// Weight f32 [C][K] -> bf16 B-fragment layout, [ks][n] major (padded K).
// (kept for module stability; superseded by wconv_all below)
// ---------------------------------------------------------------------------
__global__ void wconv_frag(const float* __restrict__ src, unsigned short* __restrict__ dst,
                           int C, int K, int Kp)
{
    int NTC = C >> 4;
    int total = C * Kp;
    for (int i = blockIdx.x * blockDim.x + threadIdx.x; i < total; i += gridDim.x * blockDim.x) {
        int j  = i & 7;
        int l  = (i >> 3) & 63;
        int t  = i >> 9;
        int n  = t % NTC;
        int ks = t / NTC;
        int col = n * 16 + (l & 15);
        int k   = ks * 32 + ((l >> 4) << 3) + j;
        dst[i] = (k < K) ? f2bf(src[(long)col * K + k]) : (unsigned short)0;
    }
}

// ---------------------------------------------------------------------------
// All four weight conversions in one launch (grid-stride over 110592 elems).
// ---------------------------------------------------------------------------
__global__ void wconv_all(const float* __restrict__ Wu, const float* __restrict__ Wi,
                          const float* __restrict__ We, const float* __restrict__ Wv,
                          unsigned short* __restrict__ wub, unsigned short* __restrict__ wib,
                          unsigned short* __restrict__ web, unsigned short* __restrict__ wvb)
{
    for (int i = blockIdx.x * blockDim.x + threadIdx.x; i < 110592; i += gridDim.x * blockDim.x) {
        const float* src; unsigned short* dst; int C, K, ii;
        if (i < 40960)      { src = Wu; dst = wub; C = 128; K = 300; ii = i; }
        else if (i < 69632) { src = Wi; dst = wib; C = 128; K = 200; ii = i - 40960; }
        else if (i < 77824) { src = We; dst = web; C = 128; K = 64;  ii = i - 69632; }
        else                { src = Wv; dst = wvb; C = 256; K = 128; ii = i - 77824; }
        int NTC = C >> 4;
        int j  = ii & 7;
        int l  = (ii >> 3) & 63;
        int t  = ii >> 9;
        int n  = t % NTC;
        int ks = t / NTC;
        int col = n * 16 + (l & 15);
        int k   = ks * 32 + ((l >> 4) << 3) + j;
        dst[ii] = (k < K) ? f2bf(src[(long)col * K + k]) : (unsigned short)0;
    }
}

// ---------------------------------------------------------------------------
// Setup: folded weights + wq/wk zero-padded 16-col bf16 B-fragments.
// ---------------------------------------------------------------------------
__global__ void eff_setup(const float* __restrict__ Wq, const float* __restrict__ bq,
                          const float* __restrict__ na_item,
                          const float* __restrict__ Wk, const float* __restrict__ bk,
                          const float* __restrict__ na_user,
                          const float* __restrict__ W_merge, const float* __restrict__ b_merge,
                          const float* __restrict__ W_eattn, const float* __restrict__ b_eattn,
                          float* __restrict__ wq_eff, float* __restrict__ bq_eff,
                          float* __restrict__ wk_eff, float* __restrict__ bk_eff,
                          float* __restrict__ Wcomb, float* __restrict__ cmv,
                          unsigned short* __restrict__ wqf, unsigned short* __restrict__ wkf)
{
    int tid = threadIdx.x;
    for (int idx = tid; idx < 1024; idx += 256) {
        int h = idx >> 7, k = idx & 127;
        float s1 = 0.f, s2 = 0.f, s3 = 0.f;
        for (int d = 0; d < 32; ++d) {
            s1 += Wq[(h * 32 + d) * 128 + k] * na_item[d];
            s2 += Wk[(h * 32 + d) * 128 + k] * na_user[d];
        }
        for (int j = 0; j < 8; ++j)
            s3 += W_merge[h * 16 + 8 + j] * W_eattn[j * 128 + k];
        wq_eff[idx] = s1;
        wk_eff[idx] = s2;
        Wcomb[idx]  = s3;
    }
    if (tid < 8) {
        float s1 = 0.f, s2 = 0.f, s3 = b_merge[tid];
        for (int d = 0; d < 32; ++d) {
            s1 += bq[tid * 32 + d] * na_item[d];
            s2 += bk[tid * 32 + d] * na_user[d];
        }
        for (int j = 0; j < 8; ++j) s3 += W_merge[tid * 16 + 8 + j] * b_eattn[j];
        bq_eff[tid] = s1;
        bk_eff[tid] = s2;
        cmv[tid]    = s3;
    }
    __syncthreads();
    for (int idx = tid; idx < 2048; idx += 256) {
        int j  = idx & 7;
        int l  = (idx >> 3) & 63;
        int ks = idx >> 9;
        int col = l & 15;
        int k   = ks * 32 + ((l >> 4) << 3) + j;
        wqf[idx] = (col < 8) ? f2bf(wq_eff[col * 128 + k]) : (unsigned short)0;
        wkf[idx] = (col < 8) ? f2bf(wk_eff[col * 128 + k]) : (unsigned short)0;
    }
}

// ---------------------------------------------------------------------------
// CSR build: histogram (separate kernel, as in r13) -> single-block scan ->
// scatter.  scan1 replaces blocksum+scanoff+rowstart.
// ---------------------------------------------------------------------------
__global__ void hist_kernel(const int* __restrict__ dst_idx, int* __restrict__ cnt)
{
    int e = blockIdx.x * blockDim.x + threadIdx.x;
    if (e < NE) atomicAdd(&cnt[dst_idx[e]], 1);
}

__global__ __launch_bounds__(1024) void scan1(const int* __restrict__ cnt,
                                              int* __restrict__ row_start,
                                              int* __restrict__ cursor)
{
    __shared__ int sm[1024];
    const int t = threadIdx.x;
    const int CH = 98;                       // 1024*98 = 100352 >= N_DST
    const int base = t * CH;
    int tot = 0;
    for (int i = 0; i < CH; ++i) {
        int idx = base + i;
        if (idx < N_DST) tot += cnt[idx];
    }
    sm[t] = tot;
    __syncthreads();
    for (int off = 1; off < 1024; off <<= 1) {
        int v = (t >= off) ? sm[t - off] : 0;
        __syncthreads();
        sm[t] += v;
        __syncthreads();
    }
    int run = sm[t] - tot;                   // exclusive prefix
    for (int i = 0; i < CH; ++i) {
        int idx = base + i;
        if (idx < N_DST) {
            row_start[idx] = run;
            cursor[idx]    = run;
            run += cnt[idx];
        }
    }
    if (t == 0) row_start[N_DST] = NE;
}

__global__ void scatter_kernel(const int* __restrict__ dst_idx,
                               int* __restrict__ cursor, int* __restrict__ eorder)
{
    int e = blockIdx.x * blockDim.x + threadIdx.x;
    if (e >= NE) return;
    int pos = atomicAdd(&cursor[dst_idx[e]], 1);
    eorder[pos] = e;
}

// ---------------------------------------------------------------------------
// Mega-fused gather v4: batch-issued register cache + fp8 P/esf decode.
// ---------------------------------------------------------------------------
__global__ __launch_bounds__(256) void fused_gather4(
    const int* __restrict__ row_start, const int* __restrict__ eorder,
    const int* __restrict__ src_idx,
    const unsigned char* __restrict__ Pb, const unsigned char* __restrict__ esfb,
    const unsigned short* __restrict__ vb,
    const float* __restrict__ aq, const float* __restrict__ ak,
    const float* __restrict__ Wcomb, const float* __restrict__ cmv,
    const float* __restrict__ W_merge,
    const float* __restrict__ ln_gamma, const float* __restrict__ ln_beta,
    float* __restrict__ out)
{
    int gw   = (blockIdx.x * blockDim.x + threadIdx.x) >> 6;
    int lane = threadIdx.x & 63;
    if (gw >= N_DST) return;
    const int dst = gw;
    const int r0 = row_start[dst], r1 = row_start[dst + 1];
    const int deg = r1 - r0;
    const int ch = lane * 2;
    const int hl = lane & 7;
    const int g  = lane >> 3;
    const float rsc = 0.17677669529663687f;   // 1/sqrt(32)

    float ax = 0.f, ay = 0.f, az = 0.f, aw = 0.f;

    if (deg > 0) {
        float wc0[8], wc1[8];
#pragma unroll
        for (int h = 0; h < 8; ++h) {
            wc0[h] = Wcomb[h * 128 + ch];
            wc1[h] = Wcomb[h * 128 + ch + 1];
        }
        const float wself = W_merge[g * 16 + hl];
        const float cmg   = cmv[g];
        const float aqh   = aq[(long)dst * 8 + hl];

        if (deg <= 8) {
            int eo[8], sr[8];
            unsigned int pu[8], su[8];
            float akv[8];
            uint2 vv[8];
#pragma unroll
            for (int j = 0; j < 8; ++j) { pu[j] = 0u; su[j] = 0u; akv[j] = 0.f;
                                          vv[j] = make_uint2(0u, 0u); }
#pragma unroll
            for (int j = 0; j < 8; ++j) if (j < deg) eo[j] = eorder[r0 + j];
#pragma unroll
            for (int j = 0; j < 8; ++j) if (j < deg) sr[j] = src_idx[eo[j]];
#pragma unroll
            for (int j = 0; j < 8; ++j) if (j < deg) {
                pu[j]  = *(const unsigned short*)&Pb[(long)eo[j] * 128 + ch];
                su[j]  = *(const unsigned short*)&esfb[(long)sr[j] * 128 + ch];
                akv[j] = ak[(long)sr[j] * 8 + hl];
                vv[j]  = *(const uint2*)&vb[(long)sr[j] * 256 + lane * 4];
            }
            float z0[8], z1[8], ex[8];
            float s1x = 0.f, s1y = 0.f, s2l = 0.f;
#pragma unroll
            for (int j = 0; j < 8; ++j) {
                z0[j] = e52f(pu[j] & 0xFFu) * e52f(su[j] & 0xFFu);
                z1[j] = e52f(pu[j] >> 8)    * e52f(su[j] >> 8);
                s1x += z0[j];
                s1y += z1[j];
                float e = expf((akv[j] + aqh) * rsc);
                ex[j] = (j < deg) ? e : 0.f;
                s2l += ex[j];
            }
            const float i1x = 1.0f / fmaxf(s1x, 1e-35f);
            const float i1y = 1.0f / fmaxf(s1y, 1e-35f);
            const float i2  = 1.0f / s2l;
#pragma unroll
            for (int j = 0; j < 8; ++j) if (j < deg) {
                float t0 = z0[j] * i1x;
                float t1 = z1[j] * i1y;
                float part[8];
#pragma unroll
                for (int h = 0; h < 8; ++h) part[h] = t0 * wc0[h] + t1 * wc1[h];
                int b0 = lane & 1, b1 = (lane >> 1) & 1, b2 = (lane >> 2) & 1;
                float u0 = (b0 ? part[1] : part[0]) + __shfl_xor(b0 ? part[0] : part[1], 1);
                float u1 = (b0 ? part[3] : part[2]) + __shfl_xor(b0 ? part[2] : part[3], 1);
                float u2 = (b0 ? part[5] : part[4]) + __shfl_xor(b0 ? part[4] : part[5], 1);
                float u3 = (b0 ? part[7] : part[6]) + __shfl_xor(b0 ? part[6] : part[7], 1);
                float w0 = (b1 ? u1 : u0) + __shfl_xor(b1 ? u0 : u1, 2);
                float w1 = (b1 ? u3 : u2) + __shfl_xor(b1 ? u2 : u3, 2);
                float ts = (b2 ? w1 : w0) + __shfl_xor(b2 ? w0 : w1, 4);
                ts += __shfl_xor(ts, 8);
                ts += __shfl_xor(ts, 16);
                ts += __shfl_xor(ts, 32);
                float ms = wself * (ex[j] * i2);
                ms += __shfl_xor(ms, 1);
                ms += __shfl_xor(ms, 2);
                ms += __shfl_xor(ms, 4);
                float mm = cmg + ms + __shfl(ts, g);
                ax += mm * bflo(vv[j].x); ay += mm * bfhi(vv[j].x);
                az += mm * bflo(vv[j].y); aw += mm * bfhi(vv[j].y);
            }
        } else {
            float s1x = 0.f, s1y = 0.f, s2l = 0.f;
            for (int j = r0; j < r1; ++j) {
                int eo  = eorder[j];
                int src = src_idx[eo];
                unsigned int pu = *(const unsigned short*)&Pb[(long)eo * 128 + ch];
                unsigned int su = *(const unsigned short*)&esfb[(long)src * 128 + ch];
                float akh = ak[(long)src * 8 + hl];
                s1x += e52f(pu & 0xFFu) * e52f(su & 0xFFu);
                s1y += e52f(pu >> 8)    * e52f(su >> 8);
                s2l += expf((akh + aqh) * rsc);
            }
            const float i1x = 1.0f / fmaxf(s1x, 1e-35f);
            const float i1y = 1.0f / fmaxf(s1y, 1e-35f);
            const float i2  = 1.0f / s2l;
            for (int j = r0; j < r1; ++j) {
                int eo  = eorder[j];
                int src = src_idx[eo];
                unsigned int pu = *(const unsigned short*)&Pb[(long)eo * 128 + ch];
                unsigned int su = *(const unsigned short*)&esfb[(long)src * 128 + ch];
                float akh = ak[(long)src * 8 + hl];
                uint2 vv = *(const uint2*)&vb[(long)src * 256 + lane * 4];
                float t0 = e52f(pu & 0xFFu) * e52f(su & 0xFFu) * i1x;
                float t1 = e52f(pu >> 8)    * e52f(su >> 8)    * i1y;
                float part[8];
#pragma unroll
                for (int h = 0; h < 8; ++h) part[h] = t0 * wc0[h] + t1 * wc1[h];
                int b0 = lane & 1, b1 = (lane >> 1) & 1, b2 = (lane >> 2) & 1;
                float u0 = (b0 ? part[1] : part[0]) + __shfl_xor(b0 ? part[0] : part[1], 1);
                float u1 = (b0 ? part[3] : part[2]) + __shfl_xor(b0 ? part[2] : part[3], 1);
                float u2 = (b0 ? part[5] : part[4]) + __shfl_xor(b0 ? part[4] : part[5], 1);
                float u3 = (b0 ? part[7] : part[6]) + __shfl_xor(b0 ? part[6] : part[7], 1);
                float w0 = (b1 ? u1 : u0) + __shfl_xor(b1 ? u0 : u1, 2);
                float w1 = (b1 ? u3 : u2) + __shfl_xor(b1 ? u2 : u3, 2);
                float ts = (b2 ? w1 : w0) + __shfl_xor(b2 ? w0 : w1, 4);
                ts += __shfl_xor(ts, 8);
                ts += __shfl_xor(ts, 16);
                ts += __shfl_xor(ts, 32);
                float ms = wself * (expf((akh + aqh) * rsc) * i2);
                ms += __shfl_xor(ms, 1);
                ms += __shfl_xor(ms, 2);
                ms += __shfl_xor(ms, 4);
                float mm = cmg + ms + __shfl(ts, g);
                ax += mm * bflo(vv.x); ay += mm * bfhi(vv.x);
                az += mm * bflo(vv.y); aw += mm * bfhi(vv.y);
            }
        }
    }

    float s = ax + ay + az + aw;
    float q = ax * ax + ay * ay + az * az + aw * aw;
#pragma unroll
    for (int off = 32; off > 0; off >>= 1) {
        s += __shfl_xor(s, off);
        q += __shfl_xor(q, off);
    }
    float mu  = s * (1.0f / 256.0f);
    float var = q * (1.0f / 256.0f) - mu * mu;
    float inv = rsqrtf(var + 1e-5f);
    float4 gg = *(const float4*)&ln_gamma[lane * 4];
    float4 bb = *(const float4*)&ln_beta[lane * 4];
    float4 o;
    o.x = (ax - mu) * inv * gg.x + bb.x;
    o.y = (ay - mu) * inv * gg.y + bb.y;
    o.z = (az - mu) * inv * gg.z + bb.z;
    o.w = (aw - mu) * inv * gg.w + bb.w;
    *(float4*)&out[(long)dst * 256 + lane * 4] = o;
}

// ---------------------------------------------------------------------------
extern "C" void kernel_launch(void* const* d_in, const int* in_sizes, int n_in,
                              void* d_out, int out_size, void* d_ws, size_t ws_size,
                              hipStream_t stream)
{
    const float* x_user        = (const float*)d_in[0];
    const float* x_item        = (const float*)d_in[1];
    const float* node_emb_user = (const float*)d_in[2];
    const float* edge_emb      = (const float*)d_in[3];
    const float* edge_feats    = (const float*)d_in[4];
    const int*   src_idx       = (const int*)d_in[5];
    const int*   dst_idx       = (const int*)d_in[6];
    const float* W_nf_user     = (const float*)d_in[7];
    const float* b_nf_user     = (const float*)d_in[8];
    const float* W_nf_item     = (const float*)d_in[9];
    const float* b_nf_item     = (const float*)d_in[10];
    const float* W_ef          = (const float*)d_in[11];
    const float* b_ef          = (const float*)d_in[12];
    const float* W_eattn       = (const float*)d_in[13];
    const float* b_eattn       = (const float*)d_in[14];
    const float* W_merge       = (const float*)d_in[15];
    const float* b_merge       = (const float*)d_in[16];
    const float* W_q           = (const float*)d_in[17];
    const float* b_q           = (const float*)d_in[18];
    const float* W_k           = (const float*)d_in[19];
    const float* b_k           = (const float*)d_in[20];
    const float* W_v           = (const float*)d_in[21];
    const float* b_v           = (const float*)d_in[22];
    const float* W_na_user     = (const float*)d_in[23];
    const float* W_na_item     = (const float*)d_in[24];
    const float* ln_gamma      = (const float*)d_in[25];
    const float* ln_beta       = (const float*)d_in[26];

    // fp8 buffers first (byte-addressed), then 16B-aligned bf16/f32 sections
    unsigned char* esf8 = (unsigned char*)d_ws;            // 25,600,000 B
    unsigned char* P8   = esf8 + 25600000;                 // 51,200,000 B
    unsigned short* v_b = (unsigned short*)(P8 + 51200000);// 51,200,000 u16 (16B-aligned)
    float* fz     = (float*)(v_b + 51200000);
    float* aq     = fz;                            // 800,000
    float* ak     = aq + 800000;                   // 1,600,000
    float* wq_eff = ak + 1600000;                  // 1024
    float* wk_eff = wq_eff + 1024;                 // 1024
    float* bq_eff = wk_eff + 1024;                 // 16
    float* bk_eff = bq_eff + 16;                   // 16
    float* Wcomb  = bk_eff + 16;                   // 1024
    float* cmv    = Wcomb + 1024;                  // 8
    int*   cnt       = (int*)(cmv + 8);            // N_DST
    int*   row_start = cnt + N_DST;                // N_DST + 1
    int*   cursor    = row_start + N_DST + 1;      // N_DST
    int*   eorder    = cursor + N_DST;             // NE
    unsigned short* wub = (unsigned short*)(((uintptr_t)(eorder + NE) + 15) & ~(uintptr_t)15);
    unsigned short* wib = wub + 128 * 320;
    unsigned short* web = wib + 128 * 224;
    unsigned short* wvb = web + 128 * 64;          // 256*128
    unsigned short* wqf = wvb + 256 * 128;         // 2048
    unsigned short* wkf = wqf + 2048;              // 2048
    size_t needed = (size_t)((char*)(wkf + 2048) - (char*)d_ws);
    if (ws_size < needed) {
        fprintf(stderr, "kernel_launch: ws_size %zu < needed %zu\n", ws_size, needed);
        return;
    }

    hipMemsetAsync(cnt, 0, N_DST * sizeof(int), stream);

    eff_setup<<<1, 256, 0, stream>>>(W_q, b_q, W_na_item, W_k, b_k, W_na_user,
                                     W_merge, b_merge, W_eattn, b_eattn,
                                     wq_eff, bq_eff, wk_eff, bk_eff, Wcomb, cmv,
                                     wqf, wkf);

    wconv_all<<<108, 1024, 0, stream>>>(W_nf_user, W_nf_item, W_ef, W_v,
                                        wub, wib, web, wvb);

    // merged triple-GEMM (interleaved block types; 7 buckets of 782 — r13 form)
    gemm_all<<<5474, 256, 0, stream>>>(
        x_user, wub, b_nf_user, node_emb_user, edge_emb,
        esf8, wvb, b_v, v_b, wkf, ak,
        x_item, wib, b_nf_item, wqf, aq,
        edge_feats, web, b_ef, P8);

    // CSR build: hist (separate) -> single-block scan -> scatter
    hist_kernel<<<1563, 256, 0, stream>>>(dst_idx, cnt);
    scan1<<<1, 1024, 0, stream>>>(cnt, row_start, cursor);
    scatter_kernel<<<1563, 256, 0, stream>>>(dst_idx, cursor, eorder);

    // mega-fused gather + LN
    fused_gather4<<<25000, 256, 0, stream>>>(
        row_start, eorder, src_idx, P8, esf8, v_b, aq, ak,
        Wcomb, cmv, W_merge, ln_gamma, ln_beta, (float*)d_out);
}

// Round 18
// 581.451 us; speedup vs baseline: 1.4179x; 1.4179x over previous
//
#include <hip/hip_runtime.h>
#include <hip/hip_fp16.h>
#include <math.h>
#include <stdio.h>
#include <stdint.h>

#define N_SRC 200000
#define N_DST 100000
#define NE    400000
// IN=128, H=8, D=32, H*D=256

#define SCAN_CHUNK 1024
#define NSCAN ((N_DST + SCAN_CHUNK - 1) / SCAN_CHUNK)   // 98

typedef short bf16x8 __attribute__((ext_vector_type(8)));
typedef float f32x4 __attribute__((ext_vector_type(4)));

__device__ __forceinline__ float bflo(unsigned int u) { return __uint_as_float(u << 16); }
__device__ __forceinline__ float bfhi(unsigned int u) { return __uint_as_float(u & 0xFFFF0000u); }
__device__ __forceinline__ unsigned short f2bf(float f) {
    unsigned int u = __float_as_uint(f);
    u += 0x7FFFu + ((u >> 16) & 1u);       // round-to-nearest-even
    return (unsigned short)(u >> 16);
}
__device__ __forceinline__ unsigned int packbf(float f0, float f1) {
    return __builtin_amdgcn_perm(__float_as_uint(f1), __float_as_uint(f0), 0x07060302u);
}
// f32 -> fp8 e5m2 (via f16 RNE, then RNE to top 8 bits)
__device__ __forceinline__ unsigned char f2e5(float f) {
    __half h = __float2half(f);
    unsigned short b = *reinterpret_cast<unsigned short*>(&h);
    b = (unsigned short)(b + 0x7Fu + ((b >> 8) & 1u));
    return (unsigned char)(b >> 8);
}
// fp8 e5m2 -> f32
__device__ __forceinline__ float e52f(unsigned int b8) {
    unsigned short h = (unsigned short)(b8 << 8);
    __half hh = *reinterpret_cast<__half*>(&h);
    return __half2float(hh);
}
// async global->LDS DMA, 16 bytes per lane
__device__ __forceinline__ void gl2lds(const void* g, void* l) {
    __builtin_amdgcn_global_load_lds(
        (const __attribute__((address_space(1))) unsigned int*)g,
        (__attribute__((address_space(3))) unsigned int*)l, 16, 0, 0);
}

// ---------------------------------------------------------------------------
// Generic fused GEMM body (device function, one tile of 128 rows x 128 cols).
// A via gl_lds double-buffer (source-swizzled chunks); B-fragments loaded to
// REGISTERS per step from L2 (issued BEFORE the A-stage so compiler pb-waits
// leave the prefetched A in flight: entry 4 oldA -> +8 B -> +4 newA;
// vmcnt(12) drains exactly oldA; pb uses drain to vmcnt(4)).
// Epilogue writes bf16 (out_lin) / fp8-e5m2 exp (out_exp); optional T-tile in
// LDS feeding FUSEV (v = sf@Wv^T + b_v) and DOT (8-head row dots).
// NOTE: counted vmcnt is fragile to codegen perturbation — this body and its
// caller gemm_all must stay byte-identical to the r13-verified form.
// ---------------------------------------------------------------------------
template<int K, int KP, int NT, bool FUSEV, bool DOT>
__device__ __forceinline__ void gemm_body(
    int tileY, char* LDSB,
    const float* __restrict__ Ap, const unsigned short* __restrict__ Wf,
    const float* __restrict__ bias, const float* __restrict__ add_n,
    const float* __restrict__ add_c,
    unsigned short* __restrict__ out_lin, unsigned char* __restrict__ out_exp,
    const unsigned short* __restrict__ wvfrag, const float* __restrict__ bv,
    unsigned short* __restrict__ vout,
    const unsigned short* __restrict__ dotfrag, float* __restrict__ dotout,
    int N, int C)
{
    constexpr int KST = KP / 32;
    char* As = LDSB;            // 2 x 16384 (f32 A step)
    char* T  = LDSB;            // 128 x 256B bf16 sf tile (reused after main)

    const int tid  = threadIdx.x;
    const int lane = tid & 63;
    const int wv   = tid >> 6;
    const int fr   = lane & 15;
    const int fq   = lane >> 4;
    const int row0 = tileY * 128;
    const int NTC  = C / 16;

    f32x4 acc[2][NT];
#pragma unroll
    for (int m = 0; m < 2; ++m)
#pragma unroll
        for (int n = 0; n < NT; ++n) acc[m][n] = (f32x4){0.f, 0.f, 0.f, 0.f};

    const int csw = (lane & 7) ^ (lane >> 3);   // source-swizzled chunk (A stage)

    auto stageA = [&](int buf, int ks) {
        char* ab = As + buf * 16384;
        const char* Af = (const char*)Ap;
#pragma unroll
        for (int q = 0; q < 4; ++q) {
            int i   = wv * 4 + q;
            int row = i * 8 + (lane >> 3);
            int rr  = row0 + row; if (rr >= N) rr = N - 1;
            int kk  = ks * 32 + csw * 4;
            long off = (long)rr * K + ((kk + 4 <= K) ? kk : 0);
            gl2lds(Af + off * 4, ab + i * 1024 + lane * 16);
        }
    };

    stageA(0, 0);
    for (int ks = 0; ks < KST; ++ks) {
        const int cur = ks & 1;
        // B fragments -> registers (issued FIRST so pb-waits don't drain newA)
        uint4 pb[NT];
#pragma unroll
        for (int n = 0; n < NT; ++n)
            pb[n] = *(const uint4*)&Wf[(((size_t)ks * NTC + n) * 64 + lane) * 8];
        if (ks + 1 < KST) {
            stageA(cur ^ 1, ks + 1);
            asm volatile("s_waitcnt vmcnt(12)" ::: "memory");
        } else {
            asm volatile("s_waitcnt vmcnt(8)" ::: "memory");
        }
        __builtin_amdgcn_s_barrier();

        const char* ab = As + cur * 16384;
        const int rA = fr & 7;
        float4 f0 = *(const float4*)(ab + (wv * 32 +      fr) * 128 + ((2 * fq)     ^ rA) * 16);
        float4 f1 = *(const float4*)(ab + (wv * 32 +      fr) * 128 + ((2 * fq + 1) ^ rA) * 16);
        float4 f2 = *(const float4*)(ab + (wv * 32 + 16 + fr) * 128 + ((2 * fq)     ^ rA) * 16);
        float4 f3 = *(const float4*)(ab + (wv * 32 + 16 + fr) * 128 + ((2 * fq + 1) ^ rA) * 16);
        uint4 u0, u1;
        u0.x = packbf(f0.x, f0.y); u0.y = packbf(f0.z, f0.w);
        u0.z = packbf(f1.x, f1.y); u0.w = packbf(f1.z, f1.w);
        u1.x = packbf(f2.x, f2.y); u1.y = packbf(f2.z, f2.w);
        u1.z = packbf(f3.x, f3.y); u1.w = packbf(f3.z, f3.w);
        bf16x8 a0 = *(bf16x8*)&u0;
        bf16x8 a1 = *(bf16x8*)&u1;
#pragma unroll
        for (int n = 0; n < NT; ++n) {
            acc[0][n] = __builtin_amdgcn_mfma_f32_16x16x32_bf16(a0, *(bf16x8*)&pb[n], acc[0][n], 0, 0, 0);
            acc[1][n] = __builtin_amdgcn_mfma_f32_16x16x32_bf16(a1, *(bf16x8*)&pb[n], acc[1][n], 0, 0, 0);
        }
        asm volatile("s_waitcnt lgkmcnt(0)" ::: "memory");
        __builtin_amdgcn_s_barrier();
    }

    // ---- main epilogue: D col = lane&15, row = (lane>>4)*4 + reg (m89/m91) ----
    float bc[NT];
#pragma unroll
    for (int n = 0; n < NT; ++n) {
        int col = n * 16 + fr;
        float b = 0.f;
        if (bias)  b += bias[col];
        if (add_c) b += add_c[col];
        bc[n] = b;
    }
#pragma unroll
    for (int m = 0; m < 2; ++m) {
#pragma unroll
        for (int j = 0; j < 4; ++j) {
            int rl  = wv * 32 + m * 16 + fq * 4 + j;   // local row
            int row = row0 + rl;
            bool rok = (row < N);
#pragma unroll
            for (int n = 0; n < NT; ++n) {
                int col = n * 16 + fr;
                float v = acc[m][n][j] + bc[n];
                if (add_n && rok) v += add_n[(long)row * C + col];
                unsigned short bf = f2bf(v);
                if (FUSEV || DOT) {
                    int c = col >> 3;
                    *(unsigned short*)(T + rl * 256 + ((c ^ (rl & 7)) * 16) + (col & 7) * 2) = bf;
                }
                if (rok) {
                    long o = (long)row * C + col;
                    if (out_lin) out_lin[o] = bf;
                    if (out_exp) out_exp[o] = f2e5(expf(v));
                }
            }
        }
    }

    if (FUSEV || DOT) {
        __syncthreads();    // T fully written
        auto tfrag = [&](int r, int c) -> bf16x8 {
            return *(const bf16x8*)(T + r * 256 + ((c ^ (r & 7)) * 16));
        };
        if (DOT) {
            f32x4 da[2];
            da[0] = (f32x4){0.f, 0.f, 0.f, 0.f};
            da[1] = (f32x4){0.f, 0.f, 0.f, 0.f};
#pragma unroll
            for (int ks = 0; ks < 4; ++ks) {
                bf16x8 bf = *(const bf16x8*)&dotfrag[((size_t)ks * 64 + lane) * 8];
                bf16x8 t0 = tfrag(wv * 32 +      fr, ks * 4 + fq);
                bf16x8 t1 = tfrag(wv * 32 + 16 + fr, ks * 4 + fq);
                da[0] = __builtin_amdgcn_mfma_f32_16x16x32_bf16(t0, bf, da[0], 0, 0, 0);
                da[1] = __builtin_amdgcn_mfma_f32_16x16x32_bf16(t1, bf, da[1], 0, 0, 0);
            }
#pragma unroll
            for (int m = 0; m < 2; ++m)
#pragma unroll
                for (int j = 0; j < 4; ++j) {
                    int row = row0 + wv * 32 + m * 16 + fq * 4 + j;
                    if (fr < 8 && row < N) dotout[(long)row * 8 + fr] = da[m][j];
                }
        }
        if (FUSEV) {
#pragma unroll
            for (int half = 0; half < 2; ++half) {
                f32x4 va[2][8];
#pragma unroll
                for (int m = 0; m < 2; ++m)
#pragma unroll
                    for (int n = 0; n < 8; ++n) va[m][n] = (f32x4){0.f, 0.f, 0.f, 0.f};
#pragma unroll
                for (int ks = 0; ks < 4; ++ks) {
                    bf16x8 t0 = tfrag(wv * 32 +      fr, ks * 4 + fq);
                    bf16x8 t1 = tfrag(wv * 32 + 16 + fr, ks * 4 + fq);
                    uint4 vb4[8];
#pragma unroll
                    for (int n = 0; n < 8; ++n)
                        vb4[n] = *(const uint4*)&wvfrag[(((size_t)ks * 16 + half * 8 + n) * 64 + lane) * 8];
#pragma unroll
                    for (int n = 0; n < 8; ++n) {
                        va[0][n] = __builtin_amdgcn_mfma_f32_16x16x32_bf16(t0, *(bf16x8*)&vb4[n], va[0][n], 0, 0, 0);
                        va[1][n] = __builtin_amdgcn_mfma_f32_16x16x32_bf16(t1, *(bf16x8*)&vb4[n], va[1][n], 0, 0, 0);
                    }
                }
#pragma unroll
                for (int m = 0; m < 2; ++m)
#pragma unroll
                    for (int j = 0; j < 4; ++j) {
                        int row = row0 + wv * 32 + m * 16 + fq * 4 + j;
                        if (row >= N) continue;
#pragma unroll
                        for (int n = 0; n < 8; ++n) {
                            int col = half * 128 + n * 16 + fr;
                            vout[(long)row * 256 + col] = f2bf(va[m][n][j] + bv[col]);
                        }
                    }
            }
        }
    }
}

// ---------------------------------------------------------------------------
// Merged triple-GEMM dispatch — BYTE-IDENTICAL to round 13 (7 buckets, no
// hist inside; counted-vmcnt invariant verified in this exact form).
// ---------------------------------------------------------------------------
__global__ __launch_bounds__(256) void gemm_all(
    const float* __restrict__ x_user, const unsigned short* __restrict__ wub,
    const float* __restrict__ b_nf_user, const float* __restrict__ node_emb_user,
    const float* __restrict__ edge_emb,
    unsigned char* __restrict__ esf8,
    const unsigned short* __restrict__ wvb, const float* __restrict__ bv,
    unsigned short* __restrict__ v_b,
    const unsigned short* __restrict__ wkf, float* __restrict__ ak,
    const float* __restrict__ x_item, const unsigned short* __restrict__ wib,
    const float* __restrict__ b_nf_item,
    const unsigned short* __restrict__ wqf, float* __restrict__ aq,
    const float* __restrict__ edge_feats, const unsigned short* __restrict__ web,
    const float* __restrict__ b_ef, unsigned char* __restrict__ P8)
{
    __shared__ __align__(16) char LDSB[32768];
    int gid = blockIdx.x;
    int b = gid / 7;
    int r = gid - b * 7;
    if (r < 2) {
        int t = b * 2 + r;
        if (t < 1563)
            gemm_body<300, 320, 8, true, true>(t, LDSB,
                x_user, wub, b_nf_user, node_emb_user, edge_emb,
                nullptr, esf8, wvb, bv, v_b, wkf, ak, N_SRC, 128);
    } else if (r == 2) {
        gemm_body<200, 224, 8, false, true>(b, LDSB,
            x_item, wib, b_nf_item, nullptr, edge_emb,
            nullptr, nullptr, nullptr, nullptr, nullptr, wqf, aq, N_DST, 128);
    } else {
        int t = b * 4 + (r - 3);
        if (t < 3125)
            gemm_body<64, 64, 8, false, false>(t, LDSB,
                edge_feats, web, b_ef, nullptr, nullptr,
                nullptr, P8, nullptr, nullptr, nullptr, nullptr, nullptr, NE, 128);
    }
}

// ---------------------------------------------------------------------------
// All four weight conversions in one launch (verified correct in r17).
// ---------------------------------------------------------------------------
__global__ void wconv_all(const float* __restrict__ Wu, const float* __restrict__ Wi,
                          const float* __restrict__ We, const float* __restrict__ Wv,
                          unsigned short* __restrict__ wub, unsigned short* __restrict__ wib,
                          unsigned short* __restrict__ web, unsigned short* __restrict__ wvb)
{
    for (int i = blockIdx.x * blockDim.x + threadIdx.x; i < 110592; i += gridDim.x * blockDim.x) {
        const float* src; unsigned short* dst; int C, K, ii;
        if (i < 40960)      { src = Wu; dst = wub; C = 128; K = 300; ii = i; }
        else if (i < 69632) { src = Wi; dst = wib; C = 128; K = 200; ii = i - 40960; }
        else if (i < 77824) { src = We; dst = web; C = 128; K = 64;  ii = i - 69632; }
        else                { src = Wv; dst = wvb; C = 256; K = 128; ii = i - 77824; }
        int NTC = C >> 4;
        int j  = ii & 7;
        int l  = (ii >> 3) & 63;
        int t  = ii >> 9;
        int n  = t % NTC;
        int ks = t / NTC;
        int col = n * 16 + (l & 15);
        int k   = ks * 32 + ((l >> 4) << 3) + j;
        dst[ii] = (k < K) ? f2bf(src[(long)col * K + k]) : (unsigned short)0;
    }
}

// ---------------------------------------------------------------------------
// Setup: folded weights + wq/wk zero-padded 16-col bf16 B-fragments.
// ---------------------------------------------------------------------------
__global__ void eff_setup(const float* __restrict__ Wq, const float* __restrict__ bq,
                          const float* __restrict__ na_item,
                          const float* __restrict__ Wk, const float* __restrict__ bk,
                          const float* __restrict__ na_user,
                          const float* __restrict__ W_merge, const float* __restrict__ b_merge,
                          const float* __restrict__ W_eattn, const float* __restrict__ b_eattn,
                          float* __restrict__ wq_eff, float* __restrict__ bq_eff,
                          float* __restrict__ wk_eff, float* __restrict__ bk_eff,
                          float* __restrict__ Wcomb, float* __restrict__ cmv,
                          unsigned short* __restrict__ wqf, unsigned short* __restrict__ wkf)
{
    int tid = threadIdx.x;
    for (int idx = tid; idx < 1024; idx += 256) {
        int h = idx >> 7, k = idx & 127;
        float s1 = 0.f, s2 = 0.f, s3 = 0.f;
        for (int d = 0; d < 32; ++d) {
            s1 += Wq[(h * 32 + d) * 128 + k] * na_item[d];
            s2 += Wk[(h * 32 + d) * 128 + k] * na_user[d];
        }
        for (int j = 0; j < 8; ++j)
            s3 += W_merge[h * 16 + 8 + j] * W_eattn[j * 128 + k];
        wq_eff[idx] = s1;
        wk_eff[idx] = s2;
        Wcomb[idx]  = s3;
    }
    if (tid < 8) {
        float s1 = 0.f, s2 = 0.f, s3 = b_merge[tid];
        for (int d = 0; d < 32; ++d) {
            s1 += bq[tid * 32 + d] * na_item[d];
            s2 += bk[tid * 32 + d] * na_user[d];
        }
        for (int j = 0; j < 8; ++j) s3 += W_merge[tid * 16 + 8 + j] * b_eattn[j];
        bq_eff[tid] = s1;
        bk_eff[tid] = s2;
        cmv[tid]    = s3;
    }
    __syncthreads();
    for (int idx = tid; idx < 2048; idx += 256) {
        int j  = idx & 7;
        int l  = (idx >> 3) & 63;
        int ks = idx >> 9;
        int col = l & 15;
        int k   = ks * 32 + ((l >> 4) << 3) + j;
        wqf[idx] = (col < 8) ? f2bf(wq_eff[col * 128 + k]) : (unsigned short)0;
        wkf[idx] = (col < 8) ? f2bf(wk_eff[col * 128 + k]) : (unsigned short)0;
    }
}

// ---------------------------------------------------------------------------
// CSR build: histogram -> two-level COALESCED scan -> scatter (r13 chain;
// single-block scan1 regressed 235us due to 392B-stride uncoalesced reads).
// ---------------------------------------------------------------------------
__global__ void hist_kernel(const int* __restrict__ dst_idx, int* __restrict__ cnt)
{
    int e = blockIdx.x * blockDim.x + threadIdx.x;
    if (e < NE) atomicAdd(&cnt[dst_idx[e]], 1);
}

__global__ __launch_bounds__(256) void blocksum_kernel(const int* __restrict__ cnt,
                                                       int* __restrict__ bsum)
{
    __shared__ int sm[256];
    int b = blockIdx.x, t = threadIdx.x;
    int s = 0;
    for (int i = t; i < SCAN_CHUNK; i += 256) {
        int idx = b * SCAN_CHUNK + i;
        if (idx < N_DST) s += cnt[idx];
    }
    sm[t] = s; __syncthreads();
    for (int off = 128; off > 0; off >>= 1) {
        if (t < off) sm[t] += sm[t + off];
        __syncthreads();
    }
    if (t == 0) bsum[b] = sm[0];
}

__global__ void scanoff_kernel(const int* __restrict__ bsum, int* __restrict__ boff)
{
    if (threadIdx.x == 0) {
        int r = 0;
        for (int i = 0; i < NSCAN; ++i) { boff[i] = r; r += bsum[i]; }
    }
}

__global__ __launch_bounds__(256) void rowstart_kernel(
    const int* __restrict__ cnt, const int* __restrict__ boff,
    int* __restrict__ row_start, int* __restrict__ cursor)
{
    __shared__ int sm[256];
    int b = blockIdx.x, t = threadIdx.x;
    int base = b * SCAN_CHUNK + t * 4;
    int c[4]; int tot = 0;
#pragma unroll
    for (int j = 0; j < 4; ++j) {
        int idx = base + j;
        c[j] = (idx < N_DST) ? cnt[idx] : 0;
        tot += c[j];
    }
    sm[t] = tot; __syncthreads();
    for (int off = 1; off < 256; off <<= 1) {
        int v = (t >= off) ? sm[t - off] : 0;
        __syncthreads();
        sm[t] += v;
        __syncthreads();
    }
    int run = sm[t] - tot + boff[b];
#pragma unroll
    for (int j = 0; j < 4; ++j) {
        int idx = base + j;
        if (idx < N_DST) { row_start[idx] = run; cursor[idx] = run; run += c[j]; }
    }
    if (b == 0 && t == 0) row_start[N_DST] = NE;
}

__global__ void scatter_kernel(const int* __restrict__ dst_idx,
                               int* __restrict__ cursor, int* __restrict__ eorder)
{
    int e = blockIdx.x * blockDim.x + threadIdx.x;
    if (e >= NE) return;
    int pos = atomicAdd(&cursor[dst_idx[e]], 1);
    eorder[pos] = e;
}

// ---------------------------------------------------------------------------
// Mega-fused gather v4: batch-issued register cache + fp8 P/esf decode.
// ---------------------------------------------------------------------------
__global__ __launch_bounds__(256) void fused_gather4(
    const int* __restrict__ row_start, const int* __restrict__ eorder,
    const int* __restrict__ src_idx,
    const unsigned char* __restrict__ Pb, const unsigned char* __restrict__ esfb,
    const unsigned short* __restrict__ vb,
    const float* __restrict__ aq, const float* __restrict__ ak,
    const float* __restrict__ Wcomb, const float* __restrict__ cmv,
    const float* __restrict__ W_merge,
    const float* __restrict__ ln_gamma, const float* __restrict__ ln_beta,
    float* __restrict__ out)
{
    int gw   = (blockIdx.x * blockDim.x + threadIdx.x) >> 6;
    int lane = threadIdx.x & 63;
    if (gw >= N_DST) return;
    const int dst = gw;
    const int r0 = row_start[dst], r1 = row_start[dst + 1];
    const int deg = r1 - r0;
    const int ch = lane * 2;
    const int hl = lane & 7;
    const int g  = lane >> 3;
    const float rsc = 0.17677669529663687f;   // 1/sqrt(32)

    float ax = 0.f, ay = 0.f, az = 0.f, aw = 0.f;

    if (deg > 0) {
        float wc0[8], wc1[8];
#pragma unroll
        for (int h = 0; h < 8; ++h) {
            wc0[h] = Wcomb[h * 128 + ch];
            wc1[h] = Wcomb[h * 128 + ch + 1];
        }
        const float wself = W_merge[g * 16 + hl];
        const float cmg   = cmv[g];
        const float aqh   = aq[(long)dst * 8 + hl];

        if (deg <= 8) {
            int eo[8], sr[8];
            unsigned int pu[8], su[8];
            float akv[8];
            uint2 vv[8];
#pragma unroll
            for (int j = 0; j < 8; ++j) { pu[j] = 0u; su[j] = 0u; akv[j] = 0.f;
                                          vv[j] = make_uint2(0u, 0u); }
#pragma unroll
            for (int j = 0; j < 8; ++j) if (j < deg) eo[j] = eorder[r0 + j];
#pragma unroll
            for (int j = 0; j < 8; ++j) if (j < deg) sr[j] = src_idx[eo[j]];
#pragma unroll
            for (int j = 0; j < 8; ++j) if (j < deg) {
                pu[j]  = *(const unsigned short*)&Pb[(long)eo[j] * 128 + ch];
                su[j]  = *(const unsigned short*)&esfb[(long)sr[j] * 128 + ch];
                akv[j] = ak[(long)sr[j] * 8 + hl];
                vv[j]  = *(const uint2*)&vb[(long)sr[j] * 256 + lane * 4];
            }
            float z0[8], z1[8], ex[8];
            float s1x = 0.f, s1y = 0.f, s2l = 0.f;
#pragma unroll
            for (int j = 0; j < 8; ++j) {
                z0[j] = e52f(pu[j] & 0xFFu) * e52f(su[j] & 0xFFu);
                z1[j] = e52f(pu[j] >> 8)    * e52f(su[j] >> 8);
                s1x += z0[j];
                s1y += z1[j];
                float e = expf((akv[j] + aqh) * rsc);
                ex[j] = (j < deg) ? e : 0.f;
                s2l += ex[j];
            }
            const float i1x = 1.0f / fmaxf(s1x, 1e-35f);
            const float i1y = 1.0f / fmaxf(s1y, 1e-35f);
            const float i2  = 1.0f / s2l;
#pragma unroll
            for (int j = 0; j < 8; ++j) if (j < deg) {
                float t0 = z0[j] * i1x;
                float t1 = z1[j] * i1y;
                float part[8];
#pragma unroll
                for (int h = 0; h < 8; ++h) part[h] = t0 * wc0[h] + t1 * wc1[h];
                int b0 = lane & 1, b1 = (lane >> 1) & 1, b2 = (lane >> 2) & 1;
                float u0 = (b0 ? part[1] : part[0]) + __shfl_xor(b0 ? part[0] : part[1], 1);
                float u1 = (b0 ? part[3] : part[2]) + __shfl_xor(b0 ? part[2] : part[3], 1);
                float u2 = (b0 ? part[5] : part[4]) + __shfl_xor(b0 ? part[4] : part[5], 1);
                float u3 = (b0 ? part[7] : part[6]) + __shfl_xor(b0 ? part[6] : part[7], 1);
                float w0 = (b1 ? u1 : u0) + __shfl_xor(b1 ? u0 : u1, 2);
                float w1 = (b1 ? u3 : u2) + __shfl_xor(b1 ? u2 : u3, 2);
                float ts = (b2 ? w1 : w0) + __shfl_xor(b2 ? w0 : w1, 4);
                ts += __shfl_xor(ts, 8);
                ts += __shfl_xor(ts, 16);
                ts += __shfl_xor(ts, 32);
                float ms = wself * (ex[j] * i2);
                ms += __shfl_xor(ms, 1);
                ms += __shfl_xor(ms, 2);
                ms += __shfl_xor(ms, 4);
                float mm = cmg + ms + __shfl(ts, g);
                ax += mm * bflo(vv[j].x); ay += mm * bfhi(vv[j].x);
                az += mm * bflo(vv[j].y); aw += mm * bfhi(vv[j].y);
            }
        } else {
            float s1x = 0.f, s1y = 0.f, s2l = 0.f;
            for (int j = r0; j < r1; ++j) {
                int eo  = eorder[j];
                int src = src_idx[eo];
                unsigned int pu = *(const unsigned short*)&Pb[(long)eo * 128 + ch];
                unsigned int su = *(const unsigned short*)&esfb[(long)src * 128 + ch];
                float akh = ak[(long)src * 8 + hl];
                s1x += e52f(pu & 0xFFu) * e52f(su & 0xFFu);
                s1y += e52f(pu >> 8)    * e52f(su >> 8);
                s2l += expf((akh + aqh) * rsc);
            }
            const float i1x = 1.0f / fmaxf(s1x, 1e-35f);
            const float i1y = 1.0f / fmaxf(s1y, 1e-35f);
            const float i2  = 1.0f / s2l;
            for (int j = r0; j < r1; ++j) {
                int eo  = eorder[j];
                int src = src_idx[eo];
                unsigned int pu = *(const unsigned short*)&Pb[(long)eo * 128 + ch];
                unsigned int su = *(const unsigned short*)&esfb[(long)src * 128 + ch];
                float akh = ak[(long)src * 8 + hl];
                uint2 vv = *(const uint2*)&vb[(long)src * 256 + lane * 4];
                float t0 = e52f(pu & 0xFFu) * e52f(su & 0xFFu) * i1x;
                float t1 = e52f(pu >> 8)    * e52f(su >> 8)    * i1y;
                float part[8];
#pragma unroll
                for (int h = 0; h < 8; ++h) part[h] = t0 * wc0[h] + t1 * wc1[h];
                int b0 = lane & 1, b1 = (lane >> 1) & 1, b2 = (lane >> 2) & 1;
                float u0 = (b0 ? part[1] : part[0]) + __shfl_xor(b0 ? part[0] : part[1], 1);
                float u1 = (b0 ? part[3] : part[2]) + __shfl_xor(b0 ? part[2] : part[3], 1);
                float u2 = (b0 ? part[5] : part[4]) + __shfl_xor(b0 ? part[4] : part[5], 1);
                float u3 = (b0 ? part[7] : part[6]) + __shfl_xor(b0 ? part[6] : part[7], 1);
                float w0 = (b1 ? u1 : u0) + __shfl_xor(b1 ? u0 : u1, 2);
                float w1 = (b1 ? u3 : u2) + __shfl_xor(b1 ? u2 : u3, 2);
                float ts = (b2 ? w1 : w0) + __shfl_xor(b2 ? w0 : w1, 4);
                ts += __shfl_xor(ts, 8);
                ts += __shfl_xor(ts, 16);
                ts += __shfl_xor(ts, 32);
                float ms = wself * (expf((akh + aqh) * rsc) * i2);
                ms += __shfl_xor(ms, 1);
                ms += __shfl_xor(ms, 2);
                ms += __shfl_xor(ms, 4);
                float mm = cmg + ms + __shfl(ts, g);
                ax += mm * bflo(vv.x); ay += mm * bfhi(vv.x);
                az += mm * bflo(vv.y); aw += mm * bfhi(vv.y);
            }
        }
    }

    float s = ax + ay + az + aw;
    float q = ax * ax + ay * ay + az * az + aw * aw;
#pragma unroll
    for (int off = 32; off > 0; off >>= 1) {
        s += __shfl_xor(s, off);
        q += __shfl_xor(q, off);
    }
    float mu  = s * (1.0f / 256.0f);
    float var = q * (1.0f / 256.0f) - mu * mu;
    float inv = rsqrtf(var + 1e-5f);
    float4 gg = *(const float4*)&ln_gamma[lane * 4];
    float4 bb = *(const float4*)&ln_beta[lane * 4];
    float4 o;
    o.x = (ax - mu) * inv * gg.x + bb.x;
    o.y = (ay - mu) * inv * gg.y + bb.y;
    o.z = (az - mu) * inv * gg.z + bb.z;
    o.w = (aw - mu) * inv * gg.w + bb.w;
    *(float4*)&out[(long)dst * 256 + lane * 4] = o;
}

// ---------------------------------------------------------------------------
extern "C" void kernel_launch(void* const* d_in, const int* in_sizes, int n_in,
                              void* d_out, int out_size, void* d_ws, size_t ws_size,
                              hipStream_t stream)
{
    const float* x_user        = (const float*)d_in[0];
    const float* x_item        = (const float*)d_in[1];
    const float* node_emb_user = (const float*)d_in[2];
    const float* edge_emb      = (const float*)d_in[3];
    const float* edge_feats    = (const float*)d_in[4];
    const int*   src_idx       = (const int*)d_in[5];
    const int*   dst_idx       = (const int*)d_in[6];
    const float* W_nf_user     = (const float*)d_in[7];
    const float* b_nf_user     = (const float*)d_in[8];
    const float* W_nf_item     = (const float*)d_in[9];
    const float* b_nf_item     = (const float*)d_in[10];
    const float* W_ef          = (const float*)d_in[11];
    const float* b_ef          = (const float*)d_in[12];
    const float* W_eattn       = (const float*)d_in[13];
    const float* b_eattn       = (const float*)d_in[14];
    const float* W_merge       = (const float*)d_in[15];
    const float* b_merge       = (const float*)d_in[16];
    const float* W_q           = (const float*)d_in[17];
    const float* b_q           = (const float*)d_in[18];
    const float* W_k           = (const float*)d_in[19];
    const float* b_k           = (const float*)d_in[20];
    const float* W_v           = (const float*)d_in[21];
    const float* b_v           = (const float*)d_in[22];
    const float* W_na_user     = (const float*)d_in[23];
    const float* W_na_item     = (const float*)d_in[24];
    const float* ln_gamma      = (const float*)d_in[25];
    const float* ln_beta       = (const float*)d_in[26];

    // fp8 buffers first (byte-addressed), then 16B-aligned bf16/f32 sections
    unsigned char* esf8 = (unsigned char*)d_ws;            // 25,600,000 B
    unsigned char* P8   = esf8 + 25600000;                 // 51,200,000 B
    unsigned short* v_b = (unsigned short*)(P8 + 51200000);// 51,200,000 u16 (16B-aligned)
    float* fz     = (float*)(v_b + 51200000);
    float* aq     = fz;                            // 800,000
    float* ak     = aq + 800000;                   // 1,600,000
    float* wq_eff = ak + 1600000;                  // 1024
    float* wk_eff = wq_eff + 1024;                 // 1024
    float* bq_eff = wk_eff + 1024;                 // 16
    float* bk_eff = bq_eff + 16;                   // 16
    float* Wcomb  = bk_eff + 16;                   // 1024
    float* cmv    = Wcomb + 1024;                  // 8
    int*   cnt       = (int*)(cmv + 8);            // N_DST
    int*   bsum      = cnt + N_DST;                // 128
    int*   boff      = bsum + 128;                 // 128
    int*   row_start = boff + 128;                 // N_DST + 1
    int*   cursor    = row_start + N_DST + 1;      // N_DST
    int*   eorder    = cursor + N_DST;             // NE
    unsigned short* wub = (unsigned short*)(((uintptr_t)(eorder + NE) + 15) & ~(uintptr_t)15);
    unsigned short* wib = wub + 128 * 320;
    unsigned short* web = wib + 128 * 224;
    unsigned short* wvb = web + 128 * 64;          // 256*128
    unsigned short* wqf = wvb + 256 * 128;         // 2048
    unsigned short* wkf = wqf + 2048;              // 2048
    size_t needed = (size_t)((char*)(wkf + 2048) - (char*)d_ws);
    if (ws_size < needed) {
        fprintf(stderr, "kernel_launch: ws_size %zu < needed %zu\n", ws_size, needed);
        return;
    }

    hipMemsetAsync(cnt, 0, N_DST * sizeof(int), stream);

    eff_setup<<<1, 256, 0, stream>>>(W_q, b_q, W_na_item, W_k, b_k, W_na_user,
                                     W_merge, b_merge, W_eattn, b_eattn,
                                     wq_eff, bq_eff, wk_eff, bk_eff, Wcomb, cmv,
                                     wqf, wkf);

    wconv_all<<<108, 1024, 0, stream>>>(W_nf_user, W_nf_item, W_ef, W_v,
                                        wub, wib, web, wvb);

    // merged triple-GEMM (interleaved block types; 7 buckets of 782 — r13 form)
    gemm_all<<<5474, 256, 0, stream>>>(
        x_user, wub, b_nf_user, node_emb_user, edge_emb,
        esf8, wvb, b_v, v_b, wkf, ak,
        x_item, wib, b_nf_item, wqf, aq,
        edge_feats, web, b_ef, P8);

    // CSR build (coalesced two-level scan chain)
    hist_kernel<<<1563, 256, 0, stream>>>(dst_idx, cnt);
    blocksum_kernel<<<NSCAN, 256, 0, stream>>>(cnt, bsum);
    scanoff_kernel<<<1, 64, 0, stream>>>(bsum, boff);
    rowstart_kernel<<<NSCAN, 256, 0, stream>>>(cnt, boff, row_start, cursor);
    scatter_kernel<<<1563, 256, 0, stream>>>(dst_idx, cursor, eorder);

    // mega-fused gather + LN
    fused_gather4<<<25000, 256, 0, stream>>>(
        row_start, eorder, src_idx, P8, esf8, v_b, aq, ak,
        Wcomb, cmv, W_merge, ln_gamma, ln_beta, (float*)d_out);
}

// Round 19
// 575.808 us; speedup vs baseline: 1.4318x; 1.0098x over previous
//
#include <hip/hip_runtime.h>
#include <hip/hip_fp16.h>
#include <math.h>
#include <stdio.h>
#include <stdint.h>

#define N_SRC 200000
#define N_DST 100000
#define NE    400000
// IN=128, H=8, D=32, H*D=256

#define SCAN_CHUNK 1024
#define NSCAN ((N_DST + SCAN_CHUNK - 1) / SCAN_CHUNK)   // 98

typedef short bf16x8 __attribute__((ext_vector_type(8)));
typedef float f32x4 __attribute__((ext_vector_type(4)));

__device__ __forceinline__ float bflo(unsigned int u) { return __uint_as_float(u << 16); }
__device__ __forceinline__ float bfhi(unsigned int u) { return __uint_as_float(u & 0xFFFF0000u); }
__device__ __forceinline__ unsigned short f2bf(float f) {
    unsigned int u = __float_as_uint(f);
    u += 0x7FFFu + ((u >> 16) & 1u);       // round-to-nearest-even
    return (unsigned short)(u >> 16);
}
__device__ __forceinline__ unsigned int packbf(float f0, float f1) {
    return __builtin_amdgcn_perm(__float_as_uint(f1), __float_as_uint(f0), 0x07060302u);
}
// f32 -> fp8 e5m2 (via f16 RNE, then RNE to top 8 bits)
__device__ __forceinline__ unsigned char f2e5(float f) {
    __half h = __float2half(f);
    unsigned short b = *reinterpret_cast<unsigned short*>(&h);
    b = (unsigned short)(b + 0x7Fu + ((b >> 8) & 1u));
    return (unsigned char)(b >> 8);
}
// fp8 e5m2 -> f32
__device__ __forceinline__ float e52f(unsigned int b8) {
    unsigned short h = (unsigned short)(b8 << 8);
    __half hh = *reinterpret_cast<__half*>(&h);
    return __half2float(hh);
}
// async global->LDS DMA, 16 bytes per lane
__device__ __forceinline__ void gl2lds(const void* g, void* l) {
    __builtin_amdgcn_global_load_lds(
        (const __attribute__((address_space(1))) unsigned int*)g,
        (__attribute__((address_space(3))) unsigned int*)l, 16, 0, 0);
}

// ---------------------------------------------------------------------------
// Generic fused GEMM body — BYTE-IDENTICAL to the r13/r18-verified form.
// A via gl_lds double-buffer (source-swizzled chunks); B-fragments loaded to
// REGISTERS per step from L2 (issued BEFORE the A-stage so compiler pb-waits
// leave the prefetched A in flight: entry 4 oldA -> +8 B -> +4 newA;
// vmcnt(12) drains exactly oldA; pb uses drain to vmcnt(4)).
// NOTE: counted vmcnt is fragile to codegen perturbation — this body and its
// caller gemm_all must stay untouched (r14/r15 NaN lesson).
// ---------------------------------------------------------------------------
template<int K, int KP, int NT, bool FUSEV, bool DOT>
__device__ __forceinline__ void gemm_body(
    int tileY, char* LDSB,
    const float* __restrict__ Ap, const unsigned short* __restrict__ Wf,
    const float* __restrict__ bias, const float* __restrict__ add_n,
    const float* __restrict__ add_c,
    unsigned short* __restrict__ out_lin, unsigned char* __restrict__ out_exp,
    const unsigned short* __restrict__ wvfrag, const float* __restrict__ bv,
    unsigned short* __restrict__ vout,
    const unsigned short* __restrict__ dotfrag, float* __restrict__ dotout,
    int N, int C)
{
    constexpr int KST = KP / 32;
    char* As = LDSB;            // 2 x 16384 (f32 A step)
    char* T  = LDSB;            // 128 x 256B bf16 sf tile (reused after main)

    const int tid  = threadIdx.x;
    const int lane = tid & 63;
    const int wv   = tid >> 6;
    const int fr   = lane & 15;
    const int fq   = lane >> 4;
    const int row0 = tileY * 128;
    const int NTC  = C / 16;

    f32x4 acc[2][NT];
#pragma unroll
    for (int m = 0; m < 2; ++m)
#pragma unroll
        for (int n = 0; n < NT; ++n) acc[m][n] = (f32x4){0.f, 0.f, 0.f, 0.f};

    const int csw = (lane & 7) ^ (lane >> 3);   // source-swizzled chunk (A stage)

    auto stageA = [&](int buf, int ks) {
        char* ab = As + buf * 16384;
        const char* Af = (const char*)Ap;
#pragma unroll
        for (int q = 0; q < 4; ++q) {
            int i   = wv * 4 + q;
            int row = i * 8 + (lane >> 3);
            int rr  = row0 + row; if (rr >= N) rr = N - 1;
            int kk  = ks * 32 + csw * 4;
            long off = (long)rr * K + ((kk + 4 <= K) ? kk : 0);
            gl2lds(Af + off * 4, ab + i * 1024 + lane * 16);
        }
    };

    stageA(0, 0);
    for (int ks = 0; ks < KST; ++ks) {
        const int cur = ks & 1;
        // B fragments -> registers (issued FIRST so pb-waits don't drain newA)
        uint4 pb[NT];
#pragma unroll
        for (int n = 0; n < NT; ++n)
            pb[n] = *(const uint4*)&Wf[(((size_t)ks * NTC + n) * 64 + lane) * 8];
        if (ks + 1 < KST) {
            stageA(cur ^ 1, ks + 1);
            asm volatile("s_waitcnt vmcnt(12)" ::: "memory");
        } else {
            asm volatile("s_waitcnt vmcnt(8)" ::: "memory");
        }
        __builtin_amdgcn_s_barrier();

        const char* ab = As + cur * 16384;
        const int rA = fr & 7;
        float4 f0 = *(const float4*)(ab + (wv * 32 +      fr) * 128 + ((2 * fq)     ^ rA) * 16);
        float4 f1 = *(const float4*)(ab + (wv * 32 +      fr) * 128 + ((2 * fq + 1) ^ rA) * 16);
        float4 f2 = *(const float4*)(ab + (wv * 32 + 16 + fr) * 128 + ((2 * fq)     ^ rA) * 16);
        float4 f3 = *(const float4*)(ab + (wv * 32 + 16 + fr) * 128 + ((2 * fq + 1) ^ rA) * 16);
        uint4 u0, u1;
        u0.x = packbf(f0.x, f0.y); u0.y = packbf(f0.z, f0.w);
        u0.z = packbf(f1.x, f1.y); u0.w = packbf(f1.z, f1.w);
        u1.x = packbf(f2.x, f2.y); u1.y = packbf(f2.z, f2.w);
        u1.z = packbf(f3.x, f3.y); u1.w = packbf(f3.z, f3.w);
        bf16x8 a0 = *(bf16x8*)&u0;
        bf16x8 a1 = *(bf16x8*)&u1;
#pragma unroll
        for (int n = 0; n < NT; ++n) {
            acc[0][n] = __builtin_amdgcn_mfma_f32_16x16x32_bf16(a0, *(bf16x8*)&pb[n], acc[0][n], 0, 0, 0);
            acc[1][n] = __builtin_amdgcn_mfma_f32_16x16x32_bf16(a1, *(bf16x8*)&pb[n], acc[1][n], 0, 0, 0);
        }
        asm volatile("s_waitcnt lgkmcnt(0)" ::: "memory");
        __builtin_amdgcn_s_barrier();
    }

    // ---- main epilogue: D col = lane&15, row = (lane>>4)*4 + reg (m89/m91) ----
    float bc[NT];
#pragma unroll
    for (int n = 0; n < NT; ++n) {
        int col = n * 16 + fr;
        float b = 0.f;
        if (bias)  b += bias[col];
        if (add_c) b += add_c[col];
        bc[n] = b;
    }
#pragma unroll
    for (int m = 0; m < 2; ++m) {
#pragma unroll
        for (int j = 0; j < 4; ++j) {
            int rl  = wv * 32 + m * 16 + fq * 4 + j;   // local row
            int row = row0 + rl;
            bool rok = (row < N);
#pragma unroll
            for (int n = 0; n < NT; ++n) {
                int col = n * 16 + fr;
                float v = acc[m][n][j] + bc[n];
                if (add_n && rok) v += add_n[(long)row * C + col];
                unsigned short bf = f2bf(v);
                if (FUSEV || DOT) {
                    int c = col >> 3;
                    *(unsigned short*)(T + rl * 256 + ((c ^ (rl & 7)) * 16) + (col & 7) * 2) = bf;
                }
                if (rok) {
                    long o = (long)row * C + col;
                    if (out_lin) out_lin[o] = bf;
                    if (out_exp) out_exp[o] = f2e5(expf(v));
                }
            }
        }
    }

    if (FUSEV || DOT) {
        __syncthreads();    // T fully written
        auto tfrag = [&](int r, int c) -> bf16x8 {
            return *(const bf16x8*)(T + r * 256 + ((c ^ (r & 7)) * 16));
        };
        if (DOT) {
            f32x4 da[2];
            da[0] = (f32x4){0.f, 0.f, 0.f, 0.f};
            da[1] = (f32x4){0.f, 0.f, 0.f, 0.f};
#pragma unroll
            for (int ks = 0; ks < 4; ++ks) {
                bf16x8 bf = *(const bf16x8*)&dotfrag[((size_t)ks * 64 + lane) * 8];
                bf16x8 t0 = tfrag(wv * 32 +      fr, ks * 4 + fq);
                bf16x8 t1 = tfrag(wv * 32 + 16 + fr, ks * 4 + fq);
                da[0] = __builtin_amdgcn_mfma_f32_16x16x32_bf16(t0, bf, da[0], 0, 0, 0);
                da[1] = __builtin_amdgcn_mfma_f32_16x16x32_bf16(t1, bf, da[1], 0, 0, 0);
            }
#pragma unroll
            for (int m = 0; m < 2; ++m)
#pragma unroll
                for (int j = 0; j < 4; ++j) {
                    int row = row0 + wv * 32 + m * 16 + fq * 4 + j;
                    if (fr < 8 && row < N) dotout[(long)row * 8 + fr] = da[m][j];
                }
        }
        if (FUSEV) {
#pragma unroll
            for (int half = 0; half < 2; ++half) {
                f32x4 va[2][8];
#pragma unroll
                for (int m = 0; m < 2; ++m)
#pragma unroll
                    for (int n = 0; n < 8; ++n) va[m][n] = (f32x4){0.f, 0.f, 0.f, 0.f};
#pragma unroll
                for (int ks = 0; ks < 4; ++ks) {
                    bf16x8 t0 = tfrag(wv * 32 +      fr, ks * 4 + fq);
                    bf16x8 t1 = tfrag(wv * 32 + 16 + fr, ks * 4 + fq);
                    uint4 vb4[8];
#pragma unroll
                    for (int n = 0; n < 8; ++n)
                        vb4[n] = *(const uint4*)&wvfrag[(((size_t)ks * 16 + half * 8 + n) * 64 + lane) * 8];
#pragma unroll
                    for (int n = 0; n < 8; ++n) {
                        va[0][n] = __builtin_amdgcn_mfma_f32_16x16x32_bf16(t0, *(bf16x8*)&vb4[n], va[0][n], 0, 0, 0);
                        va[1][n] = __builtin_amdgcn_mfma_f32_16x16x32_bf16(t1, *(bf16x8*)&vb4[n], va[1][n], 0, 0, 0);
                    }
                }
#pragma unroll
                for (int m = 0; m < 2; ++m)
#pragma unroll
                    for (int j = 0; j < 4; ++j) {
                        int row = row0 + wv * 32 + m * 16 + fq * 4 + j;
                        if (row >= N) continue;
#pragma unroll
                        for (int n = 0; n < 8; ++n) {
                            int col = half * 128 + n * 16 + fr;
                            vout[(long)row * 256 + col] = f2bf(va[m][n][j] + bv[col]);
                        }
                    }
            }
        }
    }
}

// ---------------------------------------------------------------------------
// Merged triple-GEMM dispatch — BYTE-IDENTICAL to round 13/18 (7 buckets,
// no hist inside; counted-vmcnt invariant verified in this exact form).
// ---------------------------------------------------------------------------
__global__ __launch_bounds__(256) void gemm_all(
    const float* __restrict__ x_user, const unsigned short* __restrict__ wub,
    const float* __restrict__ b_nf_user, const float* __restrict__ node_emb_user,
    const float* __restrict__ edge_emb,
    unsigned char* __restrict__ esf8,
    const unsigned short* __restrict__ wvb, const float* __restrict__ bv,
    unsigned short* __restrict__ v_b,
    const unsigned short* __restrict__ wkf, float* __restrict__ ak,
    const float* __restrict__ x_item, const unsigned short* __restrict__ wib,
    const float* __restrict__ b_nf_item,
    const unsigned short* __restrict__ wqf, float* __restrict__ aq,
    const float* __restrict__ edge_feats, const unsigned short* __restrict__ web,
    const float* __restrict__ b_ef, unsigned char* __restrict__ P8)
{
    __shared__ __align__(16) char LDSB[32768];
    int gid = blockIdx.x;
    int b = gid / 7;
    int r = gid - b * 7;
    if (r < 2) {
        int t = b * 2 + r;
        if (t < 1563)
            gemm_body<300, 320, 8, true, true>(t, LDSB,
                x_user, wub, b_nf_user, node_emb_user, edge_emb,
                nullptr, esf8, wvb, bv, v_b, wkf, ak, N_SRC, 128);
    } else if (r == 2) {
        gemm_body<200, 224, 8, false, true>(b, LDSB,
            x_item, wib, b_nf_item, nullptr, edge_emb,
            nullptr, nullptr, nullptr, nullptr, nullptr, wqf, aq, N_DST, 128);
    } else {
        int t = b * 4 + (r - 3);
        if (t < 3125)
            gemm_body<64, 64, 8, false, false>(t, LDSB,
                edge_feats, web, b_ef, nullptr, nullptr,
                nullptr, P8, nullptr, nullptr, nullptr, nullptr, nullptr, NE, 128);
    }
}

// ---------------------------------------------------------------------------
// Weight conversions + edge histogram in ONE launch. Both parts are plain
// kernels (no inline-asm waits) so this cannot perturb gemm_body codegen.
// Grid-stride over 110592 conv elems + NE hist atomics.
// ---------------------------------------------------------------------------
__global__ void wconv_hist(const float* __restrict__ Wu, const float* __restrict__ Wi,
                           const float* __restrict__ We, const float* __restrict__ Wv,
                           unsigned short* __restrict__ wub, unsigned short* __restrict__ wib,
                           unsigned short* __restrict__ web, unsigned short* __restrict__ wvb,
                           const int* __restrict__ dst_idx, int* __restrict__ cnt)
{
    const int TOTAL = 110592 + NE;
    for (int i = blockIdx.x * blockDim.x + threadIdx.x; i < TOTAL; i += gridDim.x * blockDim.x) {
        if (i < 110592) {
            const float* src; unsigned short* dst; int C, K, ii;
            if (i < 40960)      { src = Wu; dst = wub; C = 128; K = 300; ii = i; }
            else if (i < 69632) { src = Wi; dst = wib; C = 128; K = 200; ii = i - 40960; }
            else if (i < 77824) { src = We; dst = web; C = 128; K = 64;  ii = i - 69632; }
            else                { src = Wv; dst = wvb; C = 256; K = 128; ii = i - 77824; }
            int NTC = C >> 4;
            int j  = ii & 7;
            int l  = (ii >> 3) & 63;
            int t  = ii >> 9;
            int n  = t % NTC;
            int ks = t / NTC;
            int col = n * 16 + (l & 15);
            int k   = ks * 32 + ((l >> 4) << 3) + j;
            dst[ii] = (k < K) ? f2bf(src[(long)col * K + k]) : (unsigned short)0;
        } else {
            int e = i - 110592;
            atomicAdd(&cnt[dst_idx[e]], 1);
        }
    }
}

// ---------------------------------------------------------------------------
// Setup: folded weights + wq/wk zero-padded 16-col bf16 B-fragments.
// ---------------------------------------------------------------------------
__global__ void eff_setup(const float* __restrict__ Wq, const float* __restrict__ bq,
                          const float* __restrict__ na_item,
                          const float* __restrict__ Wk, const float* __restrict__ bk,
                          const float* __restrict__ na_user,
                          const float* __restrict__ W_merge, const float* __restrict__ b_merge,
                          const float* __restrict__ W_eattn, const float* __restrict__ b_eattn,
                          float* __restrict__ wq_eff, float* __restrict__ bq_eff,
                          float* __restrict__ wk_eff, float* __restrict__ bk_eff,
                          float* __restrict__ Wcomb, float* __restrict__ cmv,
                          unsigned short* __restrict__ wqf, unsigned short* __restrict__ wkf)
{
    int tid = threadIdx.x;
    for (int idx = tid; idx < 1024; idx += 256) {
        int h = idx >> 7, k = idx & 127;
        float s1 = 0.f, s2 = 0.f, s3 = 0.f;
        for (int d = 0; d < 32; ++d) {
            s1 += Wq[(h * 32 + d) * 128 + k] * na_item[d];
            s2 += Wk[(h * 32 + d) * 128 + k] * na_user[d];
        }
        for (int j = 0; j < 8; ++j)
            s3 += W_merge[h * 16 + 8 + j] * W_eattn[j * 128 + k];
        wq_eff[idx] = s1;
        wk_eff[idx] = s2;
        Wcomb[idx]  = s3;
    }
    if (tid < 8) {
        float s1 = 0.f, s2 = 0.f, s3 = b_merge[tid];
        for (int d = 0; d < 32; ++d) {
            s1 += bq[tid * 32 + d] * na_item[d];
            s2 += bk[tid * 32 + d] * na_user[d];
        }
        for (int j = 0; j < 8; ++j) s3 += W_merge[tid * 16 + 8 + j] * b_eattn[j];
        bq_eff[tid] = s1;
        bk_eff[tid] = s2;
        cmv[tid]    = s3;
    }
    __syncthreads();
    for (int idx = tid; idx < 2048; idx += 256) {
        int j  = idx & 7;
        int l  = (idx >> 3) & 63;
        int ks = idx >> 9;
        int col = l & 15;
        int k   = ks * 32 + ((l >> 4) << 3) + j;
        wqf[idx] = (col < 8) ? f2bf(wq_eff[col * 128 + k]) : (unsigned short)0;
        wkf[idx] = (col < 8) ? f2bf(wk_eff[col * 128 + k]) : (unsigned short)0;
    }
}

// ---------------------------------------------------------------------------
// CSR build: coalesced two-level scan (scanoff folded into rowstart2: each
// block's thread 0 computes its own 98-entry bsum prefix — L2-resident).
// ---------------------------------------------------------------------------
__global__ __launch_bounds__(256) void blocksum_kernel(const int* __restrict__ cnt,
                                                       int* __restrict__ bsum)
{
    __shared__ int sm[256];
    int b = blockIdx.x, t = threadIdx.x;
    int s = 0;
    for (int i = t; i < SCAN_CHUNK; i += 256) {
        int idx = b * SCAN_CHUNK + i;
        if (idx < N_DST) s += cnt[idx];
    }
    sm[t] = s; __syncthreads();
    for (int off = 128; off > 0; off >>= 1) {
        if (t < off) sm[t] += sm[t + off];
        __syncthreads();
    }
    if (t == 0) bsum[b] = sm[0];
}

__global__ __launch_bounds__(256) void rowstart2(
    const int* __restrict__ cnt, const int* __restrict__ bsum,
    int* __restrict__ row_start, int* __restrict__ cursor)
{
    __shared__ int sm[256];
    __shared__ int boffs;
    int b = blockIdx.x, t = threadIdx.x;
    if (t == 0) {
        int r = 0;
        for (int i = 0; i < b; ++i) r += bsum[i];
        boffs = r;
    }
    int base = b * SCAN_CHUNK + t * 4;
    int c[4]; int tot = 0;
#pragma unroll
    for (int j = 0; j < 4; ++j) {
        int idx = base + j;
        c[j] = (idx < N_DST) ? cnt[idx] : 0;
        tot += c[j];
    }
    sm[t] = tot; __syncthreads();
    for (int off = 1; off < 256; off <<= 1) {
        int v = (t >= off) ? sm[t - off] : 0;
        __syncthreads();
        sm[t] += v;
        __syncthreads();
    }
    int run = sm[t] - tot + boffs;
#pragma unroll
    for (int j = 0; j < 4; ++j) {
        int idx = base + j;
        if (idx < N_DST) { row_start[idx] = run; cursor[idx] = run; run += c[j]; }
    }
    if (b == 0 && t == 0) row_start[N_DST] = NE;
}

__global__ void scatter_kernel(const int* __restrict__ dst_idx,
                               int* __restrict__ cursor, int* __restrict__ eorder)
{
    int e = blockIdx.x * blockDim.x + threadIdx.x;
    if (e >= NE) return;
    int pos = atomicAdd(&cursor[dst_idx[e]], 1);
    eorder[pos] = e;
}

// ---------------------------------------------------------------------------
// Mega-fused gather v4: batch-issued register cache + fp8 P/esf decode.
// ---------------------------------------------------------------------------
__global__ __launch_bounds__(256) void fused_gather4(
    const int* __restrict__ row_start, const int* __restrict__ eorder,
    const int* __restrict__ src_idx,
    const unsigned char* __restrict__ Pb, const unsigned char* __restrict__ esfb,
    const unsigned short* __restrict__ vb,
    const float* __restrict__ aq, const float* __restrict__ ak,
    const float* __restrict__ Wcomb, const float* __restrict__ cmv,
    const float* __restrict__ W_merge,
    const float* __restrict__ ln_gamma, const float* __restrict__ ln_beta,
    float* __restrict__ out)
{
    int gw   = (blockIdx.x * blockDim.x + threadIdx.x) >> 6;
    int lane = threadIdx.x & 63;
    if (gw >= N_DST) return;
    const int dst = gw;
    const int r0 = row_start[dst], r1 = row_start[dst + 1];
    const int deg = r1 - r0;
    const int ch = lane * 2;
    const int hl = lane & 7;
    const int g  = lane >> 3;
    const float rsc = 0.17677669529663687f;   // 1/sqrt(32)

    float ax = 0.f, ay = 0.f, az = 0.f, aw = 0.f;

    if (deg > 0) {
        float wc0[8], wc1[8];
#pragma unroll
        for (int h = 0; h < 8; ++h) {
            wc0[h] = Wcomb[h * 128 + ch];
            wc1[h] = Wcomb[h * 128 + ch + 1];
        }
        const float wself = W_merge[g * 16 + hl];
        const float cmg   = cmv[g];
        const float aqh   = aq[(long)dst * 8 + hl];

        if (deg <= 8) {
            int eo[8], sr[8];
            unsigned int pu[8], su[8];
            float akv[8];
            uint2 vv[8];
#pragma unroll
            for (int j = 0; j < 8; ++j) { pu[j] = 0u; su[j] = 0u; akv[j] = 0.f;
                                          vv[j] = make_uint2(0u, 0u); }
#pragma unroll
            for (int j = 0; j < 8; ++j) if (j < deg) eo[j] = eorder[r0 + j];
#pragma unroll
            for (int j = 0; j < 8; ++j) if (j < deg) sr[j] = src_idx[eo[j]];
#pragma unroll
            for (int j = 0; j < 8; ++j) if (j < deg) {
                pu[j]  = *(const unsigned short*)&Pb[(long)eo[j] * 128 + ch];
                su[j]  = *(const unsigned short*)&esfb[(long)sr[j] * 128 + ch];
                akv[j] = ak[(long)sr[j] * 8 + hl];
                vv[j]  = *(const uint2*)&vb[(long)sr[j] * 256 + lane * 4];
            }
            float z0[8], z1[8], ex[8];
            float s1x = 0.f, s1y = 0.f, s2l = 0.f;
#pragma unroll
            for (int j = 0; j < 8; ++j) {
                z0[j] = e52f(pu[j] & 0xFFu) * e52f(su[j] & 0xFFu);
                z1[j] = e52f(pu[j] >> 8)    * e52f(su[j] >> 8);
                s1x += z0[j];
                s1y += z1[j];
                float e = expf((akv[j] + aqh) * rsc);
                ex[j] = (j < deg) ? e : 0.f;
                s2l += ex[j];
            }
            const float i1x = 1.0f / fmaxf(s1x, 1e-35f);
            const float i1y = 1.0f / fmaxf(s1y, 1e-35f);
            const float i2  = 1.0f / s2l;
#pragma unroll
            for (int j = 0; j < 8; ++j) if (j < deg) {
                float t0 = z0[j] * i1x;
                float t1 = z1[j] * i1y;
                float part[8];
#pragma unroll
                for (int h = 0; h < 8; ++h) part[h] = t0 * wc0[h] + t1 * wc1[h];
                int b0 = lane & 1, b1 = (lane >> 1) & 1, b2 = (lane >> 2) & 1;
                float u0 = (b0 ? part[1] : part[0]) + __shfl_xor(b0 ? part[0] : part[1], 1);
                float u1 = (b0 ? part[3] : part[2]) + __shfl_xor(b0 ? part[2] : part[3], 1);
                float u2 = (b0 ? part[5] : part[4]) + __shfl_xor(b0 ? part[4] : part[5], 1);
                float u3 = (b0 ? part[7] : part[6]) + __shfl_xor(b0 ? part[6] : part[7], 1);
                float w0 = (b1 ? u1 : u0) + __shfl_xor(b1 ? u0 : u1, 2);
                float w1 = (b1 ? u3 : u2) + __shfl_xor(b1 ? u2 : u3, 2);
                float ts = (b2 ? w1 : w0) + __shfl_xor(b2 ? w0 : w1, 4);
                ts += __shfl_xor(ts, 8);
                ts += __shfl_xor(ts, 16);
                ts += __shfl_xor(ts, 32);
                float ms = wself * (ex[j] * i2);
                ms += __shfl_xor(ms, 1);
                ms += __shfl_xor(ms, 2);
                ms += __shfl_xor(ms, 4);
                float mm = cmg + ms + __shfl(ts, g);
                ax += mm * bflo(vv[j].x); ay += mm * bfhi(vv[j].x);
                az += mm * bflo(vv[j].y); aw += mm * bfhi(vv[j].y);
            }
        } else {
            float s1x = 0.f, s1y = 0.f, s2l = 0.f;
            for (int j = r0; j < r1; ++j) {
                int eo  = eorder[j];
                int src = src_idx[eo];
                unsigned int pu = *(const unsigned short*)&Pb[(long)eo * 128 + ch];
                unsigned int su = *(const unsigned short*)&esfb[(long)src * 128 + ch];
                float akh = ak[(long)src * 8 + hl];
                s1x += e52f(pu & 0xFFu) * e52f(su & 0xFFu);
                s1y += e52f(pu >> 8)    * e52f(su >> 8);
                s2l += expf((akh + aqh) * rsc);
            }
            const float i1x = 1.0f / fmaxf(s1x, 1e-35f);
            const float i1y = 1.0f / fmaxf(s1y, 1e-35f);
            const float i2  = 1.0f / s2l;
            for (int j = r0; j < r1; ++j) {
                int eo  = eorder[j];
                int src = src_idx[eo];
                unsigned int pu = *(const unsigned short*)&Pb[(long)eo * 128 + ch];
                unsigned int su = *(const unsigned short*)&esfb[(long)src * 128 + ch];
                float akh = ak[(long)src * 8 + hl];
                uint2 vv = *(const uint2*)&vb[(long)src * 256 + lane * 4];
                float t0 = e52f(pu & 0xFFu) * e52f(su & 0xFFu) * i1x;
                float t1 = e52f(pu >> 8)    * e52f(su >> 8)    * i1y;
                float part[8];
#pragma unroll
                for (int h = 0; h < 8; ++h) part[h] = t0 * wc0[h] + t1 * wc1[h];
                int b0 = lane & 1, b1 = (lane >> 1) & 1, b2 = (lane >> 2) & 1;
                float u0 = (b0 ? part[1] : part[0]) + __shfl_xor(b0 ? part[0] : part[1], 1);
                float u1 = (b0 ? part[3] : part[2]) + __shfl_xor(b0 ? part[2] : part[3], 1);
                float u2 = (b0 ? part[5] : part[4]) + __shfl_xor(b0 ? part[4] : part[5], 1);
                float u3 = (b0 ? part[7] : part[6]) + __shfl_xor(b0 ? part[6] : part[7], 1);
                float w0 = (b1 ? u1 : u0) + __shfl_xor(b1 ? u0 : u1, 2);
                float w1 = (b1 ? u3 : u2) + __shfl_xor(b1 ? u2 : u3, 2);
                float ts = (b2 ? w1 : w0) + __shfl_xor(b2 ? w0 : w1, 4);
                ts += __shfl_xor(ts, 8);
                ts += __shfl_xor(ts, 16);
                ts += __shfl_xor(ts, 32);
                float ms = wself * (expf((akh + aqh) * rsc) * i2);
                ms += __shfl_xor(ms, 1);
                ms += __shfl_xor(ms, 2);
                ms += __shfl_xor(ms, 4);
                float mm = cmg + ms + __shfl(ts, g);
                ax += mm * bflo(vv.x); ay += mm * bfhi(vv.x);
                az += mm * bflo(vv.y); aw += mm * bfhi(vv.y);
            }
        }
    }

    float s = ax + ay + az + aw;
    float q = ax * ax + ay * ay + az * az + aw * aw;
#pragma unroll
    for (int off = 32; off > 0; off >>= 1) {
        s += __shfl_xor(s, off);
        q += __shfl_xor(q, off);
    }
    float mu  = s * (1.0f / 256.0f);
    float var = q * (1.0f / 256.0f) - mu * mu;
    float inv = rsqrtf(var + 1e-5f);
    float4 gg = *(const float4*)&ln_gamma[lane * 4];
    float4 bb = *(const float4*)&ln_beta[lane * 4];
    float4 o;
    o.x = (ax - mu) * inv * gg.x + bb.x;
    o.y = (ay - mu) * inv * gg.y + bb.y;
    o.z = (az - mu) * inv * gg.z + bb.z;
    o.w = (aw - mu) * inv * gg.w + bb.w;
    *(float4*)&out[(long)dst * 256 + lane * 4] = o;
}

// ---------------------------------------------------------------------------
extern "C" void kernel_launch(void* const* d_in, const int* in_sizes, int n_in,
                              void* d_out, int out_size, void* d_ws, size_t ws_size,
                              hipStream_t stream)
{
    const float* x_user        = (const float*)d_in[0];
    const float* x_item        = (const float*)d_in[1];
    const float* node_emb_user = (const float*)d_in[2];
    const float* edge_emb      = (const float*)d_in[3];
    const float* edge_feats    = (const float*)d_in[4];
    const int*   src_idx       = (const int*)d_in[5];
    const int*   dst_idx       = (const int*)d_in[6];
    const float* W_nf_user     = (const float*)d_in[7];
    const float* b_nf_user     = (const float*)d_in[8];
    const float* W_nf_item     = (const float*)d_in[9];
    const float* b_nf_item     = (const float*)d_in[10];
    const float* W_ef          = (const float*)d_in[11];
    const float* b_ef          = (const float*)d_in[12];
    const float* W_eattn       = (const float*)d_in[13];
    const float* b_eattn       = (const float*)d_in[14];
    const float* W_merge       = (const float*)d_in[15];
    const float* b_merge       = (const float*)d_in[16];
    const float* W_q           = (const float*)d_in[17];
    const float* b_q           = (const float*)d_in[18];
    const float* W_k           = (const float*)d_in[19];
    const float* b_k           = (const float*)d_in[20];
    const float* W_v           = (const float*)d_in[21];
    const float* b_v           = (const float*)d_in[22];
    const float* W_na_user     = (const float*)d_in[23];
    const float* W_na_item     = (const float*)d_in[24];
    const float* ln_gamma      = (const float*)d_in[25];
    const float* ln_beta       = (const float*)d_in[26];

    // fp8 buffers first (byte-addressed), then 16B-aligned bf16/f32 sections
    unsigned char* esf8 = (unsigned char*)d_ws;            // 25,600,000 B
    unsigned char* P8   = esf8 + 25600000;                 // 51,200,000 B
    unsigned short* v_b = (unsigned short*)(P8 + 51200000);// 51,200,000 u16 (16B-aligned)
    float* fz     = (float*)(v_b + 51200000);
    float* aq     = fz;                            // 800,000
    float* ak     = aq + 800000;                   // 1,600,000
    float* wq_eff = ak + 1600000;                  // 1024
    float* wk_eff = wq_eff + 1024;                 // 1024
    float* bq_eff = wk_eff + 1024;                 // 16
    float* bk_eff = bq_eff + 16;                   // 16
    float* Wcomb  = bk_eff + 16;                   // 1024
    float* cmv    = Wcomb + 1024;                  // 8
    int*   cnt       = (int*)(cmv + 8);            // N_DST
    int*   bsum      = cnt + N_DST;                // 128
    int*   boff      = bsum + 128;                 // 128 (unused, kept for layout)
    int*   row_start = boff + 128;                 // N_DST + 1
    int*   cursor    = row_start + N_DST + 1;      // N_DST
    int*   eorder    = cursor + N_DST;             // NE
    unsigned short* wub = (unsigned short*)(((uintptr_t)(eorder + NE) + 15) & ~(uintptr_t)15);
    unsigned short* wib = wub + 128 * 320;
    unsigned short* web = wib + 128 * 224;
    unsigned short* wvb = web + 128 * 64;          // 256*128
    unsigned short* wqf = wvb + 256 * 128;         // 2048
    unsigned short* wkf = wqf + 2048;              // 2048
    size_t needed = (size_t)((char*)(wkf + 2048) - (char*)d_ws);
    if (ws_size < needed) {
        fprintf(stderr, "kernel_launch: ws_size %zu < needed %zu\n", ws_size, needed);
        return;
    }

    hipMemsetAsync(cnt, 0, N_DST * sizeof(int), stream);

    eff_setup<<<1, 256, 0, stream>>>(W_q, b_q, W_na_item, W_k, b_k, W_na_user,
                                     W_merge, b_merge, W_eattn, b_eattn,
                                     wq_eff, bq_eff, wk_eff, bk_eff, Wcomb, cmv,
                                     wqf, wkf);

    // weight conversion + edge histogram fused (both plain kernels)
    wconv_hist<<<256, 1024, 0, stream>>>(W_nf_user, W_nf_item, W_ef, W_v,
                                         wub, wib, web, wvb, dst_idx, cnt);

    // merged triple-GEMM (interleaved block types; 7 buckets of 782 — r13 form)
    gemm_all<<<5474, 256, 0, stream>>>(
        x_user, wub, b_nf_user, node_emb_user, edge_emb,
        esf8, wvb, b_v, v_b, wkf, ak,
        x_item, wib, b_nf_item, wqf, aq,
        edge_feats, web, b_ef, P8);

    // CSR build (coalesced two-level scan; scanoff folded into rowstart2)
    blocksum_kernel<<<NSCAN, 256, 0, stream>>>(cnt, bsum);
    rowstart2<<<NSCAN, 256, 0, stream>>>(cnt, bsum, row_start, cursor);
    scatter_kernel<<<1563, 256, 0, stream>>>(dst_idx, cursor, eorder);

    // mega-fused gather + LN
    fused_gather4<<<25000, 256, 0, stream>>>(
        row_start, eorder, src_idx, P8, esf8, v_b, aq, ak,
        Wcomb, cmv, W_merge, ln_gamma, ln_beta, (float*)d_out);
}

// Round 20
// 529.268 us; speedup vs baseline: 1.5577x; 1.0879x over previous
//
#include <hip/hip_runtime.h>
#include <hip/hip_fp16.h>
#include <math.h>
#include <stdio.h>
#include <stdint.h>

#define N_SRC 200000
#define N_DST 100000
#define NE    400000
// IN=128, H=8, D=32, H*D=256

#define SCAN_CHUNK 1024
#define NSCAN ((N_DST + SCAN_CHUNK - 1) / SCAN_CHUNK)   // 98

typedef short bf16x8 __attribute__((ext_vector_type(8)));
typedef float f32x4 __attribute__((ext_vector_type(4)));

__device__ __forceinline__ float bflo(unsigned int u) { return __uint_as_float(u << 16); }
__device__ __forceinline__ float bfhi(unsigned int u) { return __uint_as_float(u & 0xFFFF0000u); }
__device__ __forceinline__ unsigned short f2bf(float f) {
    unsigned int u = __float_as_uint(f);
    u += 0x7FFFu + ((u >> 16) & 1u);       // round-to-nearest-even
    return (unsigned short)(u >> 16);
}
__device__ __forceinline__ unsigned int packbf(float f0, float f1) {
    return __builtin_amdgcn_perm(__float_as_uint(f1), __float_as_uint(f0), 0x07060302u);
}
// f32 -> fp8 e5m2 (via f16 RNE, then RNE to top 8 bits)
__device__ __forceinline__ unsigned char f2e5(float f) {
    __half h = __float2half(f);
    unsigned short b = *reinterpret_cast<unsigned short*>(&h);
    b = (unsigned short)(b + 0x7Fu + ((b >> 8) & 1u));
    return (unsigned char)(b >> 8);
}
// fp8 e5m2 -> f32
__device__ __forceinline__ float e52f(unsigned int b8) {
    unsigned short h = (unsigned short)(b8 << 8);
    __half hh = *reinterpret_cast<__half*>(&h);
    return __half2float(hh);
}
// async global->LDS DMA, 16 bytes per lane
__device__ __forceinline__ void gl2lds(const void* g, void* l) {
    __builtin_amdgcn_global_load_lds(
        (const __attribute__((address_space(1))) unsigned int*)g,
        (__attribute__((address_space(3))) unsigned int*)l, 16, 0, 0);
}

// ---------------------------------------------------------------------------
// Generic fused GEMM body — BYTE-IDENTICAL to the r13/r18/r19-verified form.
// A via gl_lds double-buffer (source-swizzled chunks); B-fragments loaded to
// REGISTERS per step from L2 (issued BEFORE the A-stage so compiler pb-waits
// leave the prefetched A in flight: entry 4 oldA -> +8 B -> +4 newA;
// vmcnt(12) drains exactly oldA; pb uses drain to vmcnt(4)).
// NOTE: counted vmcnt is fragile to codegen perturbation — this body and its
// caller gemm_all must stay untouched (r14/r15 NaN lesson).
// ---------------------------------------------------------------------------
template<int K, int KP, int NT, bool FUSEV, bool DOT>
__device__ __forceinline__ void gemm_body(
    int tileY, char* LDSB,
    const float* __restrict__ Ap, const unsigned short* __restrict__ Wf,
    const float* __restrict__ bias, const float* __restrict__ add_n,
    const float* __restrict__ add_c,
    unsigned short* __restrict__ out_lin, unsigned char* __restrict__ out_exp,
    const unsigned short* __restrict__ wvfrag, const float* __restrict__ bv,
    unsigned short* __restrict__ vout,
    const unsigned short* __restrict__ dotfrag, float* __restrict__ dotout,
    int N, int C)
{
    constexpr int KST = KP / 32;
    char* As = LDSB;            // 2 x 16384 (f32 A step)
    char* T  = LDSB;            // 128 x 256B bf16 sf tile (reused after main)

    const int tid  = threadIdx.x;
    const int lane = tid & 63;
    const int wv   = tid >> 6;
    const int fr   = lane & 15;
    const int fq   = lane >> 4;
    const int row0 = tileY * 128;
    const int NTC  = C / 16;

    f32x4 acc[2][NT];
#pragma unroll
    for (int m = 0; m < 2; ++m)
#pragma unroll
        for (int n = 0; n < NT; ++n) acc[m][n] = (f32x4){0.f, 0.f, 0.f, 0.f};

    const int csw = (lane & 7) ^ (lane >> 3);   // source-swizzled chunk (A stage)

    auto stageA = [&](int buf, int ks) {
        char* ab = As + buf * 16384;
        const char* Af = (const char*)Ap;
#pragma unroll
        for (int q = 0; q < 4; ++q) {
            int i   = wv * 4 + q;
            int row = i * 8 + (lane >> 3);
            int rr  = row0 + row; if (rr >= N) rr = N - 1;
            int kk  = ks * 32 + csw * 4;
            long off = (long)rr * K + ((kk + 4 <= K) ? kk : 0);
            gl2lds(Af + off * 4, ab + i * 1024 + lane * 16);
        }
    };

    stageA(0, 0);
    for (int ks = 0; ks < KST; ++ks) {
        const int cur = ks & 1;
        // B fragments -> registers (issued FIRST so pb-waits don't drain newA)
        uint4 pb[NT];
#pragma unroll
        for (int n = 0; n < NT; ++n)
            pb[n] = *(const uint4*)&Wf[(((size_t)ks * NTC + n) * 64 + lane) * 8];
        if (ks + 1 < KST) {
            stageA(cur ^ 1, ks + 1);
            asm volatile("s_waitcnt vmcnt(12)" ::: "memory");
        } else {
            asm volatile("s_waitcnt vmcnt(8)" ::: "memory");
        }
        __builtin_amdgcn_s_barrier();

        const char* ab = As + cur * 16384;
        const int rA = fr & 7;
        float4 f0 = *(const float4*)(ab + (wv * 32 +      fr) * 128 + ((2 * fq)     ^ rA) * 16);
        float4 f1 = *(const float4*)(ab + (wv * 32 +      fr) * 128 + ((2 * fq + 1) ^ rA) * 16);
        float4 f2 = *(const float4*)(ab + (wv * 32 + 16 + fr) * 128 + ((2 * fq)     ^ rA) * 16);
        float4 f3 = *(const float4*)(ab + (wv * 32 + 16 + fr) * 128 + ((2 * fq + 1) ^ rA) * 16);
        uint4 u0, u1;
        u0.x = packbf(f0.x, f0.y); u0.y = packbf(f0.z, f0.w);
        u0.z = packbf(f1.x, f1.y); u0.w = packbf(f1.z, f1.w);
        u1.x = packbf(f2.x, f2.y); u1.y = packbf(f2.z, f2.w);
        u1.z = packbf(f3.x, f3.y); u1.w = packbf(f3.z, f3.w);
        bf16x8 a0 = *(bf16x8*)&u0;
        bf16x8 a1 = *(bf16x8*)&u1;
#pragma unroll
        for (int n = 0; n < NT; ++n) {
            acc[0][n] = __builtin_amdgcn_mfma_f32_16x16x32_bf16(a0, *(bf16x8*)&pb[n], acc[0][n], 0, 0, 0);
            acc[1][n] = __builtin_amdgcn_mfma_f32_16x16x32_bf16(a1, *(bf16x8*)&pb[n], acc[1][n], 0, 0, 0);
        }
        asm volatile("s_waitcnt lgkmcnt(0)" ::: "memory");
        __builtin_amdgcn_s_barrier();
    }

    // ---- main epilogue: D col = lane&15, row = (lane>>4)*4 + reg (m89/m91) ----
    float bc[NT];
#pragma unroll
    for (int n = 0; n < NT; ++n) {
        int col = n * 16 + fr;
        float b = 0.f;
        if (bias)  b += bias[col];
        if (add_c) b += add_c[col];
        bc[n] = b;
    }
#pragma unroll
    for (int m = 0; m < 2; ++m) {
#pragma unroll
        for (int j = 0; j < 4; ++j) {
            int rl  = wv * 32 + m * 16 + fq * 4 + j;   // local row
            int row = row0 + rl;
            bool rok = (row < N);
#pragma unroll
            for (int n = 0; n < NT; ++n) {
                int col = n * 16 + fr;
                float v = acc[m][n][j] + bc[n];
                if (add_n && rok) v += add_n[(long)row * C + col];
                unsigned short bf = f2bf(v);
                if (FUSEV || DOT) {
                    int c = col >> 3;
                    *(unsigned short*)(T + rl * 256 + ((c ^ (rl & 7)) * 16) + (col & 7) * 2) = bf;
                }
                if (rok) {
                    long o = (long)row * C + col;
                    if (out_lin) out_lin[o] = bf;
                    if (out_exp) out_exp[o] = f2e5(expf(v));
                }
            }
        }
    }

    if (FUSEV || DOT) {
        __syncthreads();    // T fully written
        auto tfrag = [&](int r, int c) -> bf16x8 {
            return *(const bf16x8*)(T + r * 256 + ((c ^ (r & 7)) * 16));
        };
        if (DOT) {
            f32x4 da[2];
            da[0] = (f32x4){0.f, 0.f, 0.f, 0.f};
            da[1] = (f32x4){0.f, 0.f, 0.f, 0.f};
#pragma unroll
            for (int ks = 0; ks < 4; ++ks) {
                bf16x8 bf = *(const bf16x8*)&dotfrag[((size_t)ks * 64 + lane) * 8];
                bf16x8 t0 = tfrag(wv * 32 +      fr, ks * 4 + fq);
                bf16x8 t1 = tfrag(wv * 32 + 16 + fr, ks * 4 + fq);
                da[0] = __builtin_amdgcn_mfma_f32_16x16x32_bf16(t0, bf, da[0], 0, 0, 0);
                da[1] = __builtin_amdgcn_mfma_f32_16x16x32_bf16(t1, bf, da[1], 0, 0, 0);
            }
#pragma unroll
            for (int m = 0; m < 2; ++m)
#pragma unroll
                for (int j = 0; j < 4; ++j) {
                    int row = row0 + wv * 32 + m * 16 + fq * 4 + j;
                    if (fr < 8 && row < N) dotout[(long)row * 8 + fr] = da[m][j];
                }
        }
        if (FUSEV) {
#pragma unroll
            for (int half = 0; half < 2; ++half) {
                f32x4 va[2][8];
#pragma unroll
                for (int m = 0; m < 2; ++m)
#pragma unroll
                    for (int n = 0; n < 8; ++n) va[m][n] = (f32x4){0.f, 0.f, 0.f, 0.f};
#pragma unroll
                for (int ks = 0; ks < 4; ++ks) {
                    bf16x8 t0 = tfrag(wv * 32 +      fr, ks * 4 + fq);
                    bf16x8 t1 = tfrag(wv * 32 + 16 + fr, ks * 4 + fq);
                    uint4 vb4[8];
#pragma unroll
                    for (int n = 0; n < 8; ++n)
                        vb4[n] = *(const uint4*)&wvfrag[(((size_t)ks * 16 + half * 8 + n) * 64 + lane) * 8];
#pragma unroll
                    for (int n = 0; n < 8; ++n) {
                        va[0][n] = __builtin_amdgcn_mfma_f32_16x16x32_bf16(t0, *(bf16x8*)&vb4[n], va[0][n], 0, 0, 0);
                        va[1][n] = __builtin_amdgcn_mfma_f32_16x16x32_bf16(t1, *(bf16x8*)&vb4[n], va[1][n], 0, 0, 0);
                    }
                }
#pragma unroll
                for (int m = 0; m < 2; ++m)
#pragma unroll
                    for (int j = 0; j < 4; ++j) {
                        int row = row0 + wv * 32 + m * 16 + fq * 4 + j;
                        if (row >= N) continue;
#pragma unroll
                        for (int n = 0; n < 8; ++n) {
                            int col = half * 128 + n * 16 + fr;
                            vout[(long)row * 256 + col] = f2bf(va[m][n][j] + bv[col]);
                        }
                    }
            }
        }
    }
}

// ---------------------------------------------------------------------------
// Merged triple-GEMM dispatch — BYTE-IDENTICAL to round 13/18/19 (7 buckets,
// no hist inside; counted-vmcnt invariant verified in this exact form).
// ---------------------------------------------------------------------------
__global__ __launch_bounds__(256) void gemm_all(
    const float* __restrict__ x_user, const unsigned short* __restrict__ wub,
    const float* __restrict__ b_nf_user, const float* __restrict__ node_emb_user,
    const float* __restrict__ edge_emb,
    unsigned char* __restrict__ esf8,
    const unsigned short* __restrict__ wvb, const float* __restrict__ bv,
    unsigned short* __restrict__ v_b,
    const unsigned short* __restrict__ wkf, float* __restrict__ ak,
    const float* __restrict__ x_item, const unsigned short* __restrict__ wib,
    const float* __restrict__ b_nf_item,
    const unsigned short* __restrict__ wqf, float* __restrict__ aq,
    const float* __restrict__ edge_feats, const unsigned short* __restrict__ web,
    const float* __restrict__ b_ef, unsigned char* __restrict__ P8)
{
    __shared__ __align__(16) char LDSB[32768];
    int gid = blockIdx.x;
    int b = gid / 7;
    int r = gid - b * 7;
    if (r < 2) {
        int t = b * 2 + r;
        if (t < 1563)
            gemm_body<300, 320, 8, true, true>(t, LDSB,
                x_user, wub, b_nf_user, node_emb_user, edge_emb,
                nullptr, esf8, wvb, bv, v_b, wkf, ak, N_SRC, 128);
    } else if (r == 2) {
        gemm_body<200, 224, 8, false, true>(b, LDSB,
            x_item, wib, b_nf_item, nullptr, edge_emb,
            nullptr, nullptr, nullptr, nullptr, nullptr, wqf, aq, N_DST, 128);
    } else {
        int t = b * 4 + (r - 3);
        if (t < 3125)
            gemm_body<64, 64, 8, false, false>(t, LDSB,
                edge_feats, web, b_ef, nullptr, nullptr,
                nullptr, P8, nullptr, nullptr, nullptr, nullptr, nullptr, NE, 128);
    }
}

// ---------------------------------------------------------------------------
// Combined prologue kernel (all plain code — cannot perturb gemm_body):
// block 0            : eff_setup (folded weights + wq/wk fragments)
// blocks 1..gridDim-1: weight conversions (110592 elems) + edge histogram (NE)
// ---------------------------------------------------------------------------
__global__ __launch_bounds__(1024) void setup_conv_hist(
    const float* __restrict__ Wq, const float* __restrict__ bq,
    const float* __restrict__ na_item,
    const float* __restrict__ Wk, const float* __restrict__ bk,
    const float* __restrict__ na_user,
    const float* __restrict__ W_merge, const float* __restrict__ b_merge,
    const float* __restrict__ W_eattn, const float* __restrict__ b_eattn,
    float* __restrict__ wq_eff, float* __restrict__ bq_eff,
    float* __restrict__ wk_eff, float* __restrict__ bk_eff,
    float* __restrict__ Wcomb, float* __restrict__ cmv,
    unsigned short* __restrict__ wqf, unsigned short* __restrict__ wkf,
    const float* __restrict__ Wu, const float* __restrict__ Wi,
    const float* __restrict__ We, const float* __restrict__ Wv,
    unsigned short* __restrict__ wub, unsigned short* __restrict__ wib,
    unsigned short* __restrict__ web, unsigned short* __restrict__ wvb,
    const int* __restrict__ dst_idx, int* __restrict__ cnt)
{
    const int tid = threadIdx.x;
    if (blockIdx.x == 0) {
        // ---- eff_setup: one element per thread (1024 elems) ----
        {
            int h = tid >> 7, k = tid & 127;
            float s1 = 0.f, s2 = 0.f, s3 = 0.f;
            for (int d = 0; d < 32; ++d) {
                s1 += Wq[(h * 32 + d) * 128 + k] * na_item[d];
                s2 += Wk[(h * 32 + d) * 128 + k] * na_user[d];
            }
            for (int j = 0; j < 8; ++j)
                s3 += W_merge[h * 16 + 8 + j] * W_eattn[j * 128 + k];
            wq_eff[tid] = s1;
            wk_eff[tid] = s2;
            Wcomb[tid]  = s3;
        }
        if (tid < 8) {
            float s1 = 0.f, s2 = 0.f, s3 = b_merge[tid];
            for (int d = 0; d < 32; ++d) {
                s1 += bq[tid * 32 + d] * na_item[d];
                s2 += bk[tid * 32 + d] * na_user[d];
            }
            for (int j = 0; j < 8; ++j) s3 += W_merge[tid * 16 + 8 + j] * b_eattn[j];
            bq_eff[tid] = s1;
            bk_eff[tid] = s2;
            cmv[tid]    = s3;
        }
        __syncthreads();
        // wq/wk fragments: 2048 elems, 2 per thread
        for (int idx = tid; idx < 2048; idx += 1024) {
            int j  = idx & 7;
            int l  = (idx >> 3) & 63;
            int ks = idx >> 9;
            int col = l & 15;
            int k   = ks * 32 + ((l >> 4) << 3) + j;
            wqf[idx] = (col < 8) ? f2bf(wq_eff[col * 128 + k]) : (unsigned short)0;
            wkf[idx] = (col < 8) ? f2bf(wk_eff[col * 128 + k]) : (unsigned short)0;
        }
        return;
    }
    // ---- blocks 1..: weight conversion + histogram (grid-stride) ----
    const int TOTAL  = 110592 + NE;
    const int stride = (gridDim.x - 1) * 1024;
    for (int i = (blockIdx.x - 1) * 1024 + tid; i < TOTAL; i += stride) {
        if (i < 110592) {
            const float* src; unsigned short* dst; int C, K, ii;
            if (i < 40960)      { src = Wu; dst = wub; C = 128; K = 300; ii = i; }
            else if (i < 69632) { src = Wi; dst = wib; C = 128; K = 200; ii = i - 40960; }
            else if (i < 77824) { src = We; dst = web; C = 128; K = 64;  ii = i - 69632; }
            else                { src = Wv; dst = wvb; C = 256; K = 128; ii = i - 77824; }
            int NTC = C >> 4;
            int j  = ii & 7;
            int l  = (ii >> 3) & 63;
            int t  = ii >> 9;
            int n  = t % NTC;
            int ks = t / NTC;
            int col = n * 16 + (l & 15);
            int k   = ks * 32 + ((l >> 4) << 3) + j;
            dst[ii] = (k < K) ? f2bf(src[(long)col * K + k]) : (unsigned short)0;
        } else {
            int e = i - 110592;
            atomicAdd(&cnt[dst_idx[e]], 1);
        }
    }
}

// ---------------------------------------------------------------------------
// CSR build: coalesced two-level scan (scanoff folded into rowstart2).
// ---------------------------------------------------------------------------
__global__ __launch_bounds__(256) void blocksum_kernel(const int* __restrict__ cnt,
                                                       int* __restrict__ bsum)
{
    __shared__ int sm[256];
    int b = blockIdx.x, t = threadIdx.x;
    int s = 0;
    for (int i = t; i < SCAN_CHUNK; i += 256) {
        int idx = b * SCAN_CHUNK + i;
        if (idx < N_DST) s += cnt[idx];
    }
    sm[t] = s; __syncthreads();
    for (int off = 128; off > 0; off >>= 1) {
        if (t < off) sm[t] += sm[t + off];
        __syncthreads();
    }
    if (t == 0) bsum[b] = sm[0];
}

__global__ __launch_bounds__(256) void rowstart2(
    const int* __restrict__ cnt, const int* __restrict__ bsum,
    int* __restrict__ row_start, int* __restrict__ cursor)
{
    __shared__ int sm[256];
    __shared__ int boffs;
    int b = blockIdx.x, t = threadIdx.x;
    if (t == 0) {
        int r = 0;
        for (int i = 0; i < b; ++i) r += bsum[i];
        boffs = r;
    }
    int base = b * SCAN_CHUNK + t * 4;
    int c[4]; int tot = 0;
#pragma unroll
    for (int j = 0; j < 4; ++j) {
        int idx = base + j;
        c[j] = (idx < N_DST) ? cnt[idx] : 0;
        tot += c[j];
    }
    sm[t] = tot; __syncthreads();
    for (int off = 1; off < 256; off <<= 1) {
        int v = (t >= off) ? sm[t - off] : 0;
        __syncthreads();
        sm[t] += v;
        __syncthreads();
    }
    int run = sm[t] - tot + boffs;
#pragma unroll
    for (int j = 0; j < 4; ++j) {
        int idx = base + j;
        if (idx < N_DST) { row_start[idx] = run; cursor[idx] = run; run += c[j]; }
    }
    if (b == 0 && t == 0) row_start[N_DST] = NE;
}

__global__ void scatter_kernel(const int* __restrict__ dst_idx,
                               int* __restrict__ cursor, int* __restrict__ eorder)
{
    int e = blockIdx.x * blockDim.x + threadIdx.x;
    if (e >= NE) return;
    int pos = atomicAdd(&cursor[dst_idx[e]], 1);
    eorder[pos] = e;
}

// ---------------------------------------------------------------------------
// Mega-fused gather v4: batch-issued register cache + fp8 P/esf decode.
// ---------------------------------------------------------------------------
__global__ __launch_bounds__(256) void fused_gather4(
    const int* __restrict__ row_start, const int* __restrict__ eorder,
    const int* __restrict__ src_idx,
    const unsigned char* __restrict__ Pb, const unsigned char* __restrict__ esfb,
    const unsigned short* __restrict__ vb,
    const float* __restrict__ aq, const float* __restrict__ ak,
    const float* __restrict__ Wcomb, const float* __restrict__ cmv,
    const float* __restrict__ W_merge,
    const float* __restrict__ ln_gamma, const float* __restrict__ ln_beta,
    float* __restrict__ out)
{
    int gw   = (blockIdx.x * blockDim.x + threadIdx.x) >> 6;
    int lane = threadIdx.x & 63;
    if (gw >= N_DST) return;
    const int dst = gw;
    const int r0 = row_start[dst], r1 = row_start[dst + 1];
    const int deg = r1 - r0;
    const int ch = lane * 2;
    const int hl = lane & 7;
    const int g  = lane >> 3;
    const float rsc = 0.17677669529663687f;   // 1/sqrt(32)

    float ax = 0.f, ay = 0.f, az = 0.f, aw = 0.f;

    if (deg > 0) {
        float wc0[8], wc1[8];
#pragma unroll
        for (int h = 0; h < 8; ++h) {
            wc0[h] = Wcomb[h * 128 + ch];
            wc1[h] = Wcomb[h * 128 + ch + 1];
        }
        const float wself = W_merge[g * 16 + hl];
        const float cmg   = cmv[g];
        const float aqh   = aq[(long)dst * 8 + hl];

        if (deg <= 8) {
            int eo[8], sr[8];
            unsigned int pu[8], su[8];
            float akv[8];
            uint2 vv[8];
#pragma unroll
            for (int j = 0; j < 8; ++j) { pu[j] = 0u; su[j] = 0u; akv[j] = 0.f;
                                          vv[j] = make_uint2(0u, 0u); }
#pragma unroll
            for (int j = 0; j < 8; ++j) if (j < deg) eo[j] = eorder[r0 + j];
#pragma unroll
            for (int j = 0; j < 8; ++j) if (j < deg) sr[j] = src_idx[eo[j]];
#pragma unroll
            for (int j = 0; j < 8; ++j) if (j < deg) {
                pu[j]  = *(const unsigned short*)&Pb[(long)eo[j] * 128 + ch];
                su[j]  = *(const unsigned short*)&esfb[(long)sr[j] * 128 + ch];
                akv[j] = ak[(long)sr[j] * 8 + hl];
                vv[j]  = *(const uint2*)&vb[(long)sr[j] * 256 + lane * 4];
            }
            float z0[8], z1[8], ex[8];
            float s1x = 0.f, s1y = 0.f, s2l = 0.f;
#pragma unroll
            for (int j = 0; j < 8; ++j) {
                z0[j] = e52f(pu[j] & 0xFFu) * e52f(su[j] & 0xFFu);
                z1[j] = e52f(pu[j] >> 8)    * e52f(su[j] >> 8);
                s1x += z0[j];
                s1y += z1[j];
                float e = expf((akv[j] + aqh) * rsc);
                ex[j] = (j < deg) ? e : 0.f;
                s2l += ex[j];
            }
            const float i1x = 1.0f / fmaxf(s1x, 1e-35f);
            const float i1y = 1.0f / fmaxf(s1y, 1e-35f);
            const float i2  = 1.0f / s2l;
#pragma unroll
            for (int j = 0; j < 8; ++j) if (j < deg) {
                float t0 = z0[j] * i1x;
                float t1 = z1[j] * i1y;
                float part[8];
#pragma unroll
                for (int h = 0; h < 8; ++h) part[h] = t0 * wc0[h] + t1 * wc1[h];
                int b0 = lane & 1, b1 = (lane >> 1) & 1, b2 = (lane >> 2) & 1;
                float u0 = (b0 ? part[1] : part[0]) + __shfl_xor(b0 ? part[0] : part[1], 1);
                float u1 = (b0 ? part[3] : part[2]) + __shfl_xor(b0 ? part[2] : part[3], 1);
                float u2 = (b0 ? part[5] : part[4]) + __shfl_xor(b0 ? part[4] : part[5], 1);
                float u3 = (b0 ? part[7] : part[6]) + __shfl_xor(b0 ? part[6] : part[7], 1);
                float w0 = (b1 ? u1 : u0) + __shfl_xor(b1 ? u0 : u1, 2);
                float w1 = (b1 ? u3 : u2) + __shfl_xor(b1 ? u2 : u3, 2);
                float ts = (b2 ? w1 : w0) + __shfl_xor(b2 ? w0 : w1, 4);
                ts += __shfl_xor(ts, 8);
                ts += __shfl_xor(ts, 16);
                ts += __shfl_xor(ts, 32);
                float ms = wself * (ex[j] * i2);
                ms += __shfl_xor(ms, 1);
                ms += __shfl_xor(ms, 2);
                ms += __shfl_xor(ms, 4);
                float mm = cmg + ms + __shfl(ts, g);
                ax += mm * bflo(vv[j].x); ay += mm * bfhi(vv[j].x);
                az += mm * bflo(vv[j].y); aw += mm * bfhi(vv[j].y);
            }
        } else {
            float s1x = 0.f, s1y = 0.f, s2l = 0.f;
            for (int j = r0; j < r1; ++j) {
                int eo  = eorder[j];
                int src = src_idx[eo];
                unsigned int pu = *(const unsigned short*)&Pb[(long)eo * 128 + ch];
                unsigned int su = *(const unsigned short*)&esfb[(long)src * 128 + ch];
                float akh = ak[(long)src * 8 + hl];
                s1x += e52f(pu & 0xFFu) * e52f(su & 0xFFu);
                s1y += e52f(pu >> 8)    * e52f(su >> 8);
                s2l += expf((akh + aqh) * rsc);
            }
            const float i1x = 1.0f / fmaxf(s1x, 1e-35f);
            const float i1y = 1.0f / fmaxf(s1y, 1e-35f);
            const float i2  = 1.0f / s2l;
            for (int j = r0; j < r1; ++j) {
                int eo  = eorder[j];
                int src = src_idx[eo];
                unsigned int pu = *(const unsigned short*)&Pb[(long)eo * 128 + ch];
                unsigned int su = *(const unsigned short*)&esfb[(long)src * 128 + ch];
                float akh = ak[(long)src * 8 + hl];
                uint2 vv = *(const uint2*)&vb[(long)src * 256 + lane * 4];
                float t0 = e52f(pu & 0xFFu) * e52f(su & 0xFFu) * i1x;
                float t1 = e52f(pu >> 8)    * e52f(su >> 8)    * i1y;
                float part[8];
#pragma unroll
                for (int h = 0; h < 8; ++h) part[h] = t0 * wc0[h] + t1 * wc1[h];
                int b0 = lane & 1, b1 = (lane >> 1) & 1, b2 = (lane >> 2) & 1;
                float u0 = (b0 ? part[1] : part[0]) + __shfl_xor(b0 ? part[0] : part[1], 1);
                float u1 = (b0 ? part[3] : part[2]) + __shfl_xor(b0 ? part[2] : part[3], 1);
                float u2 = (b0 ? part[5] : part[4]) + __shfl_xor(b0 ? part[4] : part[5], 1);
                float u3 = (b0 ? part[7] : part[6]) + __shfl_xor(b0 ? part[6] : part[7], 1);
                float w0 = (b1 ? u1 : u0) + __shfl_xor(b1 ? u0 : u1, 2);
                float w1 = (b1 ? u3 : u2) + __shfl_xor(b1 ? u2 : u3, 2);
                float ts = (b2 ? w1 : w0) + __shfl_xor(b2 ? w0 : w1, 4);
                ts += __shfl_xor(ts, 8);
                ts += __shfl_xor(ts, 16);
                ts += __shfl_xor(ts, 32);
                float ms = wself * (expf((akh + aqh) * rsc) * i2);
                ms += __shfl_xor(ms, 1);
                ms += __shfl_xor(ms, 2);
                ms += __shfl_xor(ms, 4);
                float mm = cmg + ms + __shfl(ts, g);
                ax += mm * bflo(vv.x); ay += mm * bfhi(vv.x);
                az += mm * bflo(vv.y); aw += mm * bfhi(vv.y);
            }
        }
    }

    float s = ax + ay + az + aw;
    float q = ax * ax + ay * ay + az * az + aw * aw;
#pragma unroll
    for (int off = 32; off > 0; off >>= 1) {
        s += __shfl_xor(s, off);
        q += __shfl_xor(q, off);
    }
    float mu  = s * (1.0f / 256.0f);
    float var = q * (1.0f / 256.0f) - mu * mu;
    float inv = rsqrtf(var + 1e-5f);
    float4 gg = *(const float4*)&ln_gamma[lane * 4];
    float4 bb = *(const float4*)&ln_beta[lane * 4];
    float4 o;
    o.x = (ax - mu) * inv * gg.x + bb.x;
    o.y = (ay - mu) * inv * gg.y + bb.y;
    o.z = (az - mu) * inv * gg.z + bb.z;
    o.w = (aw - mu) * inv * gg.w + bb.w;
    *(float4*)&out[(long)dst * 256 + lane * 4] = o;
}

// ---------------------------------------------------------------------------
extern "C" void kernel_launch(void* const* d_in, const int* in_sizes, int n_in,
                              void* d_out, int out_size, void* d_ws, size_t ws_size,
                              hipStream_t stream)
{
    const float* x_user        = (const float*)d_in[0];
    const float* x_item        = (const float*)d_in[1];
    const float* node_emb_user = (const float*)d_in[2];
    const float* edge_emb      = (const float*)d_in[3];
    const float* edge_feats    = (const float*)d_in[4];
    const int*   src_idx       = (const int*)d_in[5];
    const int*   dst_idx       = (const int*)d_in[6];
    const float* W_nf_user     = (const float*)d_in[7];
    const float* b_nf_user     = (const float*)d_in[8];
    const float* W_nf_item     = (const float*)d_in[9];
    const float* b_nf_item     = (const float*)d_in[10];
    const float* W_ef          = (const float*)d_in[11];
    const float* b_ef          = (const float*)d_in[12];
    const float* W_eattn       = (const float*)d_in[13];
    const float* b_eattn       = (const float*)d_in[14];
    const float* W_merge       = (const float*)d_in[15];
    const float* b_merge       = (const float*)d_in[16];
    const float* W_q           = (const float*)d_in[17];
    const float* b_q           = (const float*)d_in[18];
    const float* W_k           = (const float*)d_in[19];
    const float* b_k           = (const float*)d_in[20];
    const float* W_v           = (const float*)d_in[21];
    const float* b_v           = (const float*)d_in[22];
    const float* W_na_user     = (const float*)d_in[23];
    const float* W_na_item     = (const float*)d_in[24];
    const float* ln_gamma      = (const float*)d_in[25];
    const float* ln_beta       = (const float*)d_in[26];

    // fp8 buffers first (byte-addressed), then 16B-aligned bf16/f32 sections
    unsigned char* esf8 = (unsigned char*)d_ws;            // 25,600,000 B
    unsigned char* P8   = esf8 + 25600000;                 // 51,200,000 B
    unsigned short* v_b = (unsigned short*)(P8 + 51200000);// 51,200,000 u16 (16B-aligned)
    float* fz     = (float*)(v_b + 51200000);
    float* aq     = fz;                            // 800,000
    float* ak     = aq + 800000;                   // 1,600,000
    float* wq_eff = ak + 1600000;                  // 1024
    float* wk_eff = wq_eff + 1024;                 // 1024
    float* bq_eff = wk_eff + 1024;                 // 16
    float* bk_eff = bq_eff + 16;                   // 16
    float* Wcomb  = bk_eff + 16;                   // 1024
    float* cmv    = Wcomb + 1024;                  // 8
    int*   cnt       = (int*)(cmv + 8);            // N_DST
    int*   bsum      = cnt + N_DST;                // 128
    int*   boff      = bsum + 128;                 // 128 (unused, kept for layout)
    int*   row_start = boff + 128;                 // N_DST + 1
    int*   cursor    = row_start + N_DST + 1;      // N_DST
    int*   eorder    = cursor + N_DST;             // NE
    unsigned short* wub = (unsigned short*)(((uintptr_t)(eorder + NE) + 15) & ~(uintptr_t)15);
    unsigned short* wib = wub + 128 * 320;
    unsigned short* web = wib + 128 * 224;
    unsigned short* wvb = web + 128 * 64;          // 256*128
    unsigned short* wqf = wvb + 256 * 128;         // 2048
    unsigned short* wkf = wqf + 2048;              // 2048
    size_t needed = (size_t)((char*)(wkf + 2048) - (char*)d_ws);
    if (ws_size < needed) {
        fprintf(stderr, "kernel_launch: ws_size %zu < needed %zu\n", ws_size, needed);
        return;
    }

    hipMemsetAsync(cnt, 0, N_DST * sizeof(int), stream);

    // combined prologue: eff_setup (block 0) + weight conversion + histogram
    setup_conv_hist<<<256, 1024, 0, stream>>>(
        W_q, b_q, W_na_item, W_k, b_k, W_na_user,
        W_merge, b_merge, W_eattn, b_eattn,
        wq_eff, bq_eff, wk_eff, bk_eff, Wcomb, cmv, wqf, wkf,
        W_nf_user, W_nf_item, W_ef, W_v, wub, wib, web, wvb,
        dst_idx, cnt);

    // merged triple-GEMM (interleaved block types; 7 buckets of 782 — r13 form)
    gemm_all<<<5474, 256, 0, stream>>>(
        x_user, wub, b_nf_user, node_emb_user, edge_emb,
        esf8, wvb, b_v, v_b, wkf, ak,
        x_item, wib, b_nf_item, wqf, aq,
        edge_feats, web, b_ef, P8);

    // CSR build (coalesced two-level scan; scanoff folded into rowstart2)
    blocksum_kernel<<<NSCAN, 256, 0, stream>>>(cnt, bsum);
    rowstart2<<<NSCAN, 256, 0, stream>>>(cnt, bsum, row_start, cursor);
    scatter_kernel<<<1563, 256, 0, stream>>>(dst_idx, cursor, eorder);

    // mega-fused gather + LN
    fused_gather4<<<25000, 256, 0, stream>>>(
        row_start, eorder, src_idx, P8, esf8, v_b, aq, ak,
        Wcomb, cmv, W_merge, ln_gamma, ln_beta, (float*)d_out);
}